// Round 10
// baseline (8306.316 us; speedup 1.0000x reference)
//
#include <hip/hip_runtime.h>

typedef _Float16 f16;
typedef __attribute__((ext_vector_type(8))) _Float16 f16x8;
typedef __attribute__((ext_vector_type(4))) float f32x4;

#define E_TOTAL 160000
#define NN 20000
#define NGRAPH 64

__device__ __forceinline__ void gl_lds16(const void* g, void* l) {
    __builtin_amdgcn_global_load_lds((const __attribute__((address_space(1))) void*)g,
                                     (__attribute__((address_space(3))) void*)l, 16, 0, 0);
}

#define MFMA16(a, b, c) __builtin_amdgcn_mfma_f32_16x16x32_f16((a), (b), (c), 0, 0, 0)
#define LGKM(n) do { asm volatile("s_waitcnt lgkmcnt(" #n ")" ::: "memory"); \
                     __builtin_amdgcn_sched_barrier(0); } while (0)
#define VMW6  asm volatile("s_waitcnt vmcnt(6)" ::: "memory")
#define VMW4  asm volatile("s_waitcnt vmcnt(4)" ::: "memory")
#define VMW0  asm volatile("s_waitcnt vmcnt(0)" ::: "memory")
#define SBAR  __builtin_amdgcn_s_barrier()
#define SCHED0 __builtin_amdgcn_sched_barrier(0)

// ======== hgemmW: 256x512 block tile, BK=32, 3-deep LDS pipeline (N mult 512, K mult 32) =====
// Wave tile 128x128 (8 waves, 2M x 4N). One vmcnt(6)+barrier per K-step.
// Ledger: body(t) waits vmcnt(6) (drains s(t), keeps s(t+1) 6 ops in flight), reads tile t,
// issues s(t+2) into buf (t+2)%3 (= buf of t-1, whose reads retired before body(t-1)'s lgkm0).
__global__ __launch_bounds__(512) void hgemmW(
    int M, int N, int K,
    const f16* __restrict__ A, int lda,
    const f16* __restrict__ Bt,
    f16* __restrict__ C, int ldc,
    const float* __restrict__ bias)
{
    __shared__ __align__(16) char L[3][49152];
    const int tid  = threadIdx.x;
    const int lane = tid & 63;
    const int w    = tid >> 6;

    // T1: bijective XCD-chunked remap (m204), bm-major
    const int nbn = gridDim.x;
    const int nwg = nbn * gridDim.y;
    int d  = blockIdx.y * nbn + blockIdx.x;
    int q8 = nwg >> 3, r8 = nwg & 7;
    int xk = d & 7, j8 = d >> 3;
    int wl = (xk < r8 ? xk * (q8 + 1) : r8 * (q8 + 1) + (xk - r8) * q8) + j8;
    const int bm = (wl / nbn) * 256;
    const int bn = (wl % nbn) * 512;

    const int wm = (w >> 2) * 128;   // 2 waves along M
    const int wn = (w & 3) * 128;    // 4 waves along N
    const int fr = lane & 15;
    const int kq = lane >> 4;

    const char* Ab = (const char*)A;
    const char* Bb = (const char*)Bt;
    const size_t lda2 = (size_t)lda * 2;
    const size_t ldb2 = (size_t)K * 2;

    f32x4 acc[8][8] = {};

    // frag read offsets within a 48KB buffer: A rows [0,256) at 0, B rows [0,512) at 16384
    int aoff[8], boff[8];
#pragma unroll
    for (int mi = 0; mi < 8; ++mi) {
        int r = wm + mi * 16 + fr;
        aoff[mi] = r * 64 + ((kq ^ ((r >> 1) & 3)) << 4);
    }
#pragma unroll
    for (int ni = 0; ni < 8; ++ni) {
        int r = wn + ni * 16 + fr;
        boff[ni] = 16384 + r * 64 + ((kq ^ ((r >> 1) & 3)) << 4);
    }

    // staging: 48KB = 512 thr x 6 x 16B; rows of 64B (32 k); pre-swizzled global source
    int sdest[6];
    size_t gsrcA[2], gsrcB[4];
#pragma unroll
    for (int i = 0; i < 6; ++i) {
        int Lo = i * 8192 + tid * 16;
        int row = Lo >> 6;
        int slot = (Lo >> 4) & 3;
        int sw = (slot ^ ((row >> 1) & 3)) << 4;
        sdest[i] = Lo;
        if (i < 2) gsrcA[i] = (size_t)(bm + row) * lda2 + sw;
        else       gsrcB[i - 2] = (size_t)(bn + row - 256) * ldb2 + sw;
    }

    auto stage = [&](int t, int buf) {
        size_t kb = (size_t)t * 64;   // 32 k * 2B
#pragma unroll
        for (int i = 0; i < 2; ++i) gl_lds16(Ab + gsrcA[i] + kb, &L[buf][0] + sdest[i]);
#pragma unroll
        for (int i = 0; i < 4; ++i) gl_lds16(Bb + gsrcB[i] + kb, &L[buf][0] + sdest[2 + i]);
    };

    const int NT = K >> 5;
    stage(0, 0);
    stage(1, 1);

    int buf = 0;
    for (int t = 0; t < NT; ++t) {
        if (t + 1 < NT) { VMW6; } else { VMW0; }
        SBAR;
        const char* base = &L[buf][0];
        f16x8 a[8], b[8];
#pragma unroll
        for (int i = 0; i < 8; ++i) a[i] = *(const f16x8*)(base + aoff[i]);
#pragma unroll
        for (int i = 0; i < 8; ++i) b[i] = *(const f16x8*)(base + boff[i]);
        int nb = buf + 2; if (nb >= 3) nb -= 3;
        if (t + 2 < NT) stage(t + 2, nb);
        LGKM(0);
        __builtin_amdgcn_s_setprio(1);
#pragma unroll
        for (int mi = 0; mi < 8; ++mi)
#pragma unroll
            for (int ni = 0; ni < 8; ++ni)
                acc[mi][ni] = MFMA16(a[mi], b[ni], acc[mi][ni]);
        __builtin_amdgcn_s_setprio(0);
        ++buf; if (buf == 3) buf = 0;
    }

    // epilogue: col = bn+wn+ni*16+fr, row = bm+wm+mi*16+kq*4+r
    float bz[8];
#pragma unroll
    for (int ni = 0; ni < 8; ++ni) bz[ni] = bias[bn + wn + ni * 16 + fr];
#pragma unroll
    for (int mi = 0; mi < 8; ++mi) {
        int r0 = bm + wm + mi * 16 + kq * 4;
#pragma unroll
        for (int r = 0; r < 4; ++r) {
            int grow = r0 + r;
            if (grow >= M) continue;
#pragma unroll
            for (int ni = 0; ni < 8; ++ni) {
                int col = bn + wn + ni * 16 + fr;
                float v = fmaxf(acc[mi][ni][r] + bz[ni], 0.f);   // always RELU layers
                C[(size_t)grow * ldc + col] = (f16)v;
            }
        }
    }
}

// ---------------- hgemm8: 256x256, BK=64, pipelined-lgkm 4-phase (r9, unchanged) ----------------
template <int RELU, int AUXU, int AUXX, int SCAT>
__global__ __launch_bounds__(512, 2) void hgemm8(
    int M, int N, int K,
    const f16* __restrict__ A, int lda,
    const f16* __restrict__ Bt,
    f16* __restrict__ C, int ldc,
    const float* __restrict__ bias,
    const f16* __restrict__ utab, const int* __restrict__ uidx,
    const float* __restrict__ x9, const int* __restrict__ xidx, const float* __restrict__ W9,
    float* __restrict__ sout, const int* __restrict__ sidx)
{
    __shared__ __align__(16) char Ash[2][2][16384];
    __shared__ __align__(16) char Bsh[2][2][16384];
    __shared__ float Ws9[AUXX ? 2304 : 1];   // 9 x 256

    const int tid  = threadIdx.x;
    const int lane = tid & 63;
    const int w    = tid >> 6;

    const int nbn = gridDim.x;
    const int nwg = nbn * gridDim.y;
    int d  = blockIdx.y * nbn + blockIdx.x;
    int q8 = nwg >> 3, r8 = nwg & 7;
    int xk = d & 7, j8 = d >> 3;
    int wl = (xk < r8 ? xk * (q8 + 1) : r8 * (q8 + 1) + (xk - r8) * q8) + j8;
    const int bm = (wl / nbn) * 256;
    const int bn = (wl % nbn) * 256;

    const int wm = (w >> 2) * 128;
    const int wn = (w & 3) * 64;
    const int fr = lane & 15;
    const int kq = lane >> 4;

    const char* Ab = (const char*)A;
    const char* Bb = (const char*)Bt;
    const size_t lda2 = (size_t)lda * 2;
    const size_t ldb2 = (size_t)K * 2;

    f32x4 acc[8][4] = {};

    int aoff[8], boff[4];
#pragma unroll
    for (int mi = 0; mi < 8; ++mi) {
        int r = wm + mi * 16 + fr;
        aoff[mi] = r * 64 + ((kq ^ ((r >> 1) & 3)) << 4);
    }
#pragma unroll
    for (int ni = 0; ni < 4; ++ni) {
        int r = wn + ni * 16 + fr;
        boff[ni] = r * 64 + ((kq ^ ((r >> 1) & 3)) << 4);
    }

    int sdest[2];
    size_t gsrcA[2], gsrcB[2];
#pragma unroll
    for (int i = 0; i < 2; ++i) {
        int Lo = i * 8192 + tid * 16;
        int row = Lo >> 6;
        int s = (Lo >> 4) & 3;
        int sw = (s ^ ((row >> 1) & 3)) << 4;
        sdest[i] = Lo;
        gsrcA[i] = (size_t)(bm + row) * lda2 + sw;
        gsrcB[i] = (size_t)(bn + row) * ldb2 + sw;
    }

    const int NT = K >> 6;

    auto stageA = [&](int t, int h, int buf) {
        size_t kb = (size_t)t * 128 + h * 64;
#pragma unroll
        for (int i = 0; i < 2; ++i)
            gl_lds16(Ab + gsrcA[i] + kb, &Ash[buf][h][0] + sdest[i]);
    };
    auto stageB = [&](int t, int h, int buf) {
        size_t kb = (size_t)t * 128 + h * 64;
#pragma unroll
        for (int i = 0; i < 2; ++i)
            gl_lds16(Bb + gsrcB[i] + kb, &Bsh[buf][h][0] + sdest[i]);
    };

    f16x8 a0[4], b0[4], a1[4], a2[4], b2[4], a3[4];

    stageA(0, 0, 0); stageB(0, 0, 0); stageA(0, 1, 0); stageB(0, 1, 0);
    VMW4;
    SBAR;
#pragma unroll
    for (int i = 0; i < 4; ++i) a0[i] = *(const f16x8*)(&Ash[0][0][0] + aoff[i]);
#pragma unroll
    for (int i = 0; i < 4; ++i) b0[i] = *(const f16x8*)(&Bsh[0][0][0] + boff[i]);

    for (int t = 0; t < NT; ++t) {
        const int cur = t & 1, nxt = cur ^ 1;
        const bool pre = (t + 1 < NT);
        const char* A0 = &Ash[cur][0][0];
        const char* A1 = &Ash[cur][1][0];
        const char* B1 = &Bsh[cur][1][0];

#pragma unroll
        for (int i = 0; i < 4; ++i) a1[i] = *(const f16x8*)(A0 + aoff[4 + i]);
        if (pre) stageA(t + 1, 0, nxt);
        SBAR;
        LGKM(4);
        __builtin_amdgcn_s_setprio(1);
#pragma unroll
        for (int mi = 0; mi < 4; ++mi)
#pragma unroll
            for (int ni = 0; ni < 4; ++ni)
                acc[mi][ni] = MFMA16(a0[mi], b0[ni], acc[mi][ni]);
        __builtin_amdgcn_s_setprio(0);
        SBAR;

        if (pre) stageB(t + 1, 0, nxt);
        SBAR;
        LGKM(0);
        if (pre) { VMW4; } else { VMW0; }
        SBAR;
#pragma unroll
        for (int i = 0; i < 4; ++i) a2[i] = *(const f16x8*)(A1 + aoff[i]);
#pragma unroll
        for (int i = 0; i < 4; ++i) b2[i] = *(const f16x8*)(B1 + boff[i]);
        SCHED0;
        __builtin_amdgcn_s_setprio(1);
#pragma unroll
        for (int mi = 0; mi < 4; ++mi)
#pragma unroll
            for (int ni = 0; ni < 4; ++ni)
                acc[4 + mi][ni] = MFMA16(a1[mi], b0[ni], acc[4 + mi][ni]);
        __builtin_amdgcn_s_setprio(0);
        SBAR;

#pragma unroll
        for (int i = 0; i < 4; ++i) a3[i] = *(const f16x8*)(A1 + aoff[4 + i]);
        if (pre) stageA(t + 1, 1, nxt);
        SBAR;
        LGKM(4);
        __builtin_amdgcn_s_setprio(1);
#pragma unroll
        for (int mi = 0; mi < 4; ++mi)
#pragma unroll
            for (int ni = 0; ni < 4; ++ni)
                acc[mi][ni] = MFMA16(a2[mi], b2[ni], acc[mi][ni]);
        __builtin_amdgcn_s_setprio(0);
        SBAR;

        if (pre) stageB(t + 1, 1, nxt);
        SBAR;
        LGKM(0);
        if (pre) {
            VMW4;
            SBAR;
            const char* An = &Ash[nxt][0][0];
            const char* Bn = &Bsh[nxt][0][0];
#pragma unroll
            for (int i = 0; i < 4; ++i) a0[i] = *(const f16x8*)(An + aoff[i]);
#pragma unroll
            for (int i = 0; i < 4; ++i) b0[i] = *(const f16x8*)(Bn + boff[i]);
            SCHED0;
        }
        __builtin_amdgcn_s_setprio(1);
#pragma unroll
        for (int mi = 0; mi < 4; ++mi)
#pragma unroll
            for (int ni = 0; ni < 4; ++ni)
                acc[4 + mi][ni] = MFMA16(a3[mi], b2[ni], acc[4 + mi][ni]);
        __builtin_amdgcn_s_setprio(0);
        SBAR;
    }

    if (AUXX) {
        for (int i = tid; i < 9 * 256; i += 512)
            Ws9[i] = W9[(size_t)(i >> 8) * N + bn + (i & 255)];
        __syncthreads();
    }

#pragma unroll
    for (int mi = 0; mi < 8; ++mi) {
        int r0 = bm + wm + mi * 16 + kq * 4;
#pragma unroll
        for (int r = 0; r < 4; ++r) {
            int grow = r0 + r;
            if (grow >= M) continue;
            int ub = 0;
            if (AUXU) ub = uidx[grow];
            int sb = 0;
            if (SCAT) sb = sidx[grow];
            float xv[9];
            if (AUXX) {
                int xi = xidx ? xidx[grow] : grow;
#pragma unroll
                for (int q = 0; q < 9; ++q) xv[q] = x9[(size_t)xi * 9 + q];
            }
#pragma unroll
            for (int ni = 0; ni < 4; ++ni) {
                int lcol = wn + ni * 16 + fr;
                int col = bn + lcol;
                float v = acc[mi][ni][r] + bias[col];
                if (AUXU) v += (float)utab[(size_t)ub * N + col];
                if (AUXX) {
                    float s = 0.f;
#pragma unroll
                    for (int q = 0; q < 9; ++q) s = fmaf(xv[q], Ws9[q * 256 + lcol], s);
                    v += s;
                }
                if (RELU) v = fmaxf(v, 0.f);
                if (SCAT) {
                    atomicAdd(sout + (size_t)sb * N + col, v);
                } else {
                    C[(size_t)grow * ldc + col] = (f16)v;
                }
            }
        }
    }
}

// ---- merged weight prep ----
struct WtJob { const float* src; f16* dst; int r0, ks, n, kp, tr; };
struct WtJobs { WtJob j[10]; };

__global__ void k_wtall(WtJobs js)
{
    WtJob jb = js.j[blockIdx.y];
    size_t tot = (size_t)jb.n * jb.kp;
    size_t t = (size_t)blockIdx.x * 256 + threadIdx.x;
    if (t >= tot) return;
    if (jb.tr) {
        int n = (int)(t / jb.kp), k = (int)(t % jb.kp);
        jb.dst[t] = (k < jb.ks) ? (f16)jb.src[(size_t)(jb.r0 + k) * jb.n + n] : (f16)0.f;
    } else {
        jb.dst[t] = (f16)jb.src[t];
    }
}

__global__ void k_cbias(const float* __restrict__ n1W1, const float* __restrict__ eb5,
                        const float* __restrict__ n1b1, float* __restrict__ cb)
{
    int b = blockIdx.x * 256 + threadIdx.x;
    if (b >= 512) return;
    float s = n1b1[b];
    for (int c = 0; c < 512; ++c) s = fmaf(eb5[c], n1W1[(size_t)(9 + c) * 512 + b], s);
    cb[b] = s;
}

__global__ __launch_bounds__(256) void k_u2b(const float* __restrict__ u,
                                             const float* __restrict__ Wsel,
                                             const float* __restrict__ bsel,
                                             f16* __restrict__ u2h)
{
    __shared__ float us[4096];
    __shared__ float red[256];
    const int g = blockIdx.y;
    const int c0 = blockIdx.x * 16;
    const int col = threadIdx.x & 15;
    const int kp = threadIdx.x >> 4;
    for (int i = threadIdx.x; i < 4096; i += 256) us[i] = u[(size_t)g * 4096 + i];
    __syncthreads();
    float acc = 0.f;
    const float* wp = Wsel + (size_t)(kp * 256) * 256 + c0 + col;
#pragma unroll 8
    for (int i = 0; i < 256; ++i) acc = fmaf(us[kp * 256 + i], wp[(size_t)i * 256], acc);
    red[threadIdx.x] = acc;
    __syncthreads();
    if (kp < 8) red[threadIdx.x] += red[threadIdx.x + 128];
    __syncthreads();
    if (kp < 4) red[threadIdx.x] += red[threadIdx.x + 64];
    __syncthreads();
    if (kp < 2) red[threadIdx.x] += red[threadIdx.x + 32];
    __syncthreads();
    if (kp == 0)
        u2h[(size_t)g * 256 + c0 + col] = (f16)(red[threadIdx.x] + red[threadIdx.x + 16] + bsel[c0 + col]);
}

__global__ void k_gather19(const float* __restrict__ x, const float* __restrict__ eattr,
                           const int* __restrict__ ei, const int* __restrict__ batch,
                           f16* __restrict__ feat, int* __restrict__ ebat)
{
    size_t t = (size_t)blockIdx.x * 256 + threadIdx.x;
    if (t >= (size_t)E_TOTAL * 64) return;
    int i = (int)(t >> 6), j = (int)(t & 63);
    float v = 0.f;
    if (j < 9)        v = x[ei[i] * 9 + j];
    else if (j < 18)  v = x[ei[E_TOTAL + i] * 9 + (j - 9)];
    else if (j == 18) v = eattr[i];
    else if (j == 19) ebat[i] = batch[ei[i]];
    feat[t] = (f16)v;
}

__global__ void k_cnt(const int* __restrict__ ei, float* __restrict__ cnt)
{
    int t = blockIdx.x * 256 + threadIdx.x;
    if (t < E_TOTAL) atomicAdd(cnt + ei[t], 1.0f);
}

__global__ void k_agg(const float* __restrict__ ssum, const float* __restrict__ cnt,
                      f16* __restrict__ agg)
{
    size_t t = (size_t)blockIdx.x * 256 + threadIdx.x;
    if (t >= (size_t)NN * 512) return;
    int n = (int)(t >> 9);
    agg[t] = (f16)(ssum[t] / fmaxf(cnt[n], 1.f));
}

__global__ void k_final(const f16* __restrict__ z1, const float* __restrict__ W,
                        const float* __restrict__ b, float* __restrict__ out)
{
    int gt = blockIdx.x * 256 + threadIdx.x;
    int row = gt >> 6;
    int lane = threadIdx.x & 63;
    if (row >= NN) return;
    float s = 0.f;
#pragma unroll
    for (int c = lane; c < 512; c += 64) s += (float)z1[(size_t)row * 512 + c] * W[c];
#pragma unroll
    for (int off = 32; off; off >>= 1) s += __shfl_down(s, off);
    if (lane == 0) out[row] = s + b[0];
}

// ---------------- launch ----------------

extern "C" void kernel_launch(void* const* d_in, const int* in_sizes, int n_in,
                              void* d_out, int out_size, void* d_ws, size_t ws_size,
                              hipStream_t stream)
{
    const float* x     = (const float*)d_in[0];
    const float* eattr = (const float*)d_in[1];
    const float* u     = (const float*)d_in[2];
    const int*   ei    = (const int*)d_in[3];
    const int*   batch = (const int*)d_in[4];
    const float* Wsel  = (const float*)d_in[5];
    const float* bsel  = (const float*)d_in[6];
    const float* eW1 = (const float*)d_in[7],  * eb1 = (const float*)d_in[8];
    const float* eW2 = (const float*)d_in[9],  * eb2 = (const float*)d_in[10];
    const float* eW3 = (const float*)d_in[11], * eb3 = (const float*)d_in[12];
    const float* eW4 = (const float*)d_in[13], * eb4 = (const float*)d_in[14];
    const float* eW5 = (const float*)d_in[15], * eb5 = (const float*)d_in[16];
    const float* n1W1 = (const float*)d_in[17], * n1b1 = (const float*)d_in[18];
    const float* n1W2 = (const float*)d_in[19], * n1b2 = (const float*)d_in[20];
    const float* n2W1 = (const float*)d_in[21], * n2b1 = (const float*)d_in[22];
    const float* n2W2 = (const float*)d_in[23], * n2b2 = (const float*)d_in[24];
    float* out = (float*)d_out;

    char* ws = (char*)d_ws;
    size_t off = 0;
    auto alc = [&](size_t bytes) { char* p = ws + off; off += (bytes + 255) & ~(size_t)255; return p; };

    float* ssum  = (float*)alc((size_t)NN * 512 * 4);
    float* cnt   = (float*)alc((size_t)NN * 4);
    float* zbias = (float*)alc(1024 * 4);
    float* cbias = (float*)alc(512 * 4);
    f16* u2h     = (f16*)alc((size_t)256 * 256 * 2);
    f16* ubias_e = (f16*)alc((size_t)64 * 1024 * 2);
    f16* ubias_n = (f16*)alc((size_t)64 * 512 * 2);
    f16* eW1t19  = (f16*)alc((size_t)1024 * 64 * 2);
    f16* eW1ut   = (f16*)alc((size_t)1024 * 256 * 2);
    f16* eW2t    = (f16*)alc((size_t)1024 * 1024 * 2);
    f16* eW3t    = (f16*)alc((size_t)1024 * 1024 * 2);
    f16* eW4t    = (f16*)alc((size_t)1024 * 1024 * 2);
    f16* eW5h    = (f16*)alc((size_t)1024 * 512 * 2);
    f16* combo_t = (f16*)alc((size_t)512 * 1024 * 2);
    f16* n1W1et  = (f16*)alc((size_t)512 * 512 * 2);
    f16* n1W2t   = (f16*)alc((size_t)512 * 512 * 2);
    f16* n2W1et  = (f16*)alc((size_t)512 * 512 * 2);
    f16* n2W1ut  = (f16*)alc((size_t)512 * 256 * 2);
    f16* featAll = (f16*)alc((size_t)E_TOTAL * 64 * 2);
    int* ebatAll = (int*)alc((size_t)E_TOTAL * 4);
    size_t fixed = off;

    size_t per_edge = 4096;
    size_t need_ro = (size_t)20224 * 512 * 2 * 2;
    size_t avail = ws_size > fixed ? ws_size - fixed : 0;
    long long Cmax = (long long)(avail / per_edge);
    int C;
    if (Cmax >= E_TOTAL)      C = E_TOTAL;
    else if (Cmax >= 16384)   C = (int)((Cmax / 16384) * 16384);
    else                      C = (int)((Cmax / 256) * 256);
    if ((size_t)C * per_edge < need_ro)
        C = (int)(((need_ro + per_edge - 1) / per_edge + 255) / 256 * 256);

    f16* buf1 = (f16*)(ws + fixed);
    f16* buf2 = buf1 + (size_t)C * 1024;
    f16* agg  = (f16*)(ws + fixed);
    f16* z1   = agg + (size_t)20224 * 512;

    size_t zlen = (size_t)((char*)cbias - (char*)ssum) + 512 * 4;
    hipMemsetAsync(ssum, 0, zlen, stream);

    WtJobs js;
    js.j[0] = {eW1,  eW1t19, 0,   19,   1024, 64,   1};
    js.j[1] = {eW1,  eW1ut,  19,  256,  1024, 256,  1};
    js.j[2] = {eW2,  eW2t,   0,   1024, 1024, 1024, 1};
    js.j[3] = {eW3,  eW3t,   0,   1024, 1024, 1024, 1};
    js.j[4] = {eW4,  eW4t,   0,   1024, 1024, 1024, 1};
    js.j[5] = {n1W1, n1W1et, 9,   512,  512,  512,  1};
    js.j[6] = {n1W2, n1W2t,  0,   512,  512,  512,  1};
    js.j[7] = {n2W1, n2W1et, 9,   512,  512,  512,  1};
    js.j[8] = {n2W1, n2W1ut, 521, 256,  512,  256,  1};
    js.j[9] = {eW5,  eW5h,   0,   0,    1024, 512,  0};
    k_wtall<<<dim3(4096, 10), 256, 0, stream>>>(js);

    k_u2b<<<dim3(16, NGRAPH), 256, 0, stream>>>(u, Wsel, bsel, u2h);
    k_cnt<<<(E_TOTAL + 255) / 256, 256, 0, stream>>>(ei, cnt);
    k_cbias<<<2, 256, 0, stream>>>(n1W1, eb5, n1b1, cbias);
    k_gather19<<<(unsigned)(((size_t)E_TOTAL * 64 + 255) / 256), 256, 0, stream>>>(
        x, eattr, ei, batch, featAll, ebatAll);

    hgemm8<0,0,0,0><<<dim3(4, 1), 512, 0, stream>>>(64, 1024, 256, u2h, 256, eW1ut,
        ubias_e, 1024, eb1, nullptr, nullptr, nullptr, nullptr, nullptr, nullptr, nullptr);
    hgemm8<0,0,0,0><<<dim3(2, 1), 512, 0, stream>>>(64, 512, 256, u2h, 256, n2W1ut,
        ubias_n, 512, n2b1, nullptr, nullptr, nullptr, nullptr, nullptr, nullptr, nullptr);

    hgemm8<0,0,0,0><<<dim3(4, 2), 512, 0, stream>>>(512, 1024, 512, n1W1et, 512, eW5h,
        combo_t, 1024, zbias, nullptr, nullptr, nullptr, nullptr, nullptr, nullptr, nullptr);

    for (int e0 = 0; e0 < E_TOTAL; e0 += C) {
        int Ce = E_TOTAL - e0 < C ? E_TOTAL - e0 : C;
        int gy = (Ce + 255) / 256;

        hgemm8<1,1,0,0><<<dim3(4, gy), 512, 0, stream>>>(Ce, 1024, 64,
            featAll + (size_t)e0 * 64, 64, eW1t19,
            buf1, 1024, zbias, ubias_e, ebatAll + e0, nullptr, nullptr, nullptr, nullptr, nullptr);

        // three heavy layers: 256x512-tile kernel
        hgemmW<<<dim3(2, gy), 512, 0, stream>>>(Ce, 1024, 1024, buf1, 1024, eW2t, buf2, 1024, eb2);
        hgemmW<<<dim3(2, gy), 512, 0, stream>>>(Ce, 1024, 1024, buf2, 1024, eW3t, buf1, 1024, eb3);
        hgemmW<<<dim3(2, gy), 512, 0, stream>>>(Ce, 1024, 1024, buf1, 1024, eW4t, buf2, 1024, eb4);

        hgemm8<1,0,1,0><<<dim3(2, gy), 512, 0, stream>>>(Ce, 512, 1024, buf2, 1024, combo_t,
            buf1, 512, cbias, nullptr, nullptr, x, ei + E_TOTAL + e0, n1W1, nullptr, nullptr);

        hgemm8<1,0,0,1><<<dim3(2, gy), 512, 0, stream>>>(Ce, 512, 512, buf1, 512, n1W2t,
            nullptr, 512, n1b2, nullptr, nullptr, nullptr, nullptr, nullptr, ssum, ei + e0);
    }

    k_agg<<<(unsigned)(((size_t)NN * 512 + 255) / 256), 256, 0, stream>>>(ssum, cnt, agg);
    hgemm8<1,1,1,0><<<dim3(2, 79), 512, 0, stream>>>(NN, 512, 512, agg, 512, n2W1et,
        z1, 512, zbias, ubias_n, batch, x, nullptr, n2W1, nullptr, nullptr);
    k_final<<<(NN * 64 + 255) / 256, 256, 0, stream>>>(z1, n2W2, n2b2, out);
}

// Round 11
// 4087.920 us; speedup vs baseline: 2.0319x; 2.0319x over previous
//
#include <hip/hip_runtime.h>

typedef _Float16 f16;
typedef __attribute__((ext_vector_type(8))) _Float16 f16x8;
typedef __attribute__((ext_vector_type(4))) float f32x4;

#define E_TOTAL 160000
#define NN 20000
#define NGRAPH 64

__device__ __forceinline__ void gl_lds16(const void* g, void* l) {
    __builtin_amdgcn_global_load_lds((const __attribute__((address_space(1))) void*)g,
                                     (__attribute__((address_space(3))) void*)l, 16, 0, 0);
}

#define MFMA16(a, b, c) __builtin_amdgcn_mfma_f32_16x16x32_f16((a), (b), (c), 0, 0, 0)
#define LGKM(n) do { asm volatile("s_waitcnt lgkmcnt(" #n ")" ::: "memory"); \
                     __builtin_amdgcn_sched_barrier(0); } while (0)
#define VMW12 asm volatile("s_waitcnt vmcnt(12)" ::: "memory")
#define VMW0  asm volatile("s_waitcnt vmcnt(0)" ::: "memory")
#define SBAR  __builtin_amdgcn_s_barrier()
#define SCHED0 __builtin_amdgcn_sched_barrier(0)

struct BF { f16x8 v[4][2]; };   // [ni][ks] — all compile-time indexed

// ===== hgemmB: 256x256 tile, BK=64, 8 waves (2M x 4N), A via LDS dbuf, B direct L2->reg =====
// C[M,N] = act(A[M,lda] @ Bt[N,K]^T + bias [+aux]).  K mult of 64, N mult of 256.
// Per K-step VMEM ops/thread: 4 A gl_lds + 8 B global_load = 12. Counted vmcnt(12):
// at iter t we issue tile t+1's 12 ops (outstanding <=24), wait oldest 12 (= tile t's) ->
// A(t) in LDS + B(t) in regs; barrier; compute; barrier (WAR for buf^1 restage at t+1).
// LDS traffic/step: 128KB ds_read + 32KB write (was 256KB) -> below MFMA 2484 cyc.
template <int RELU, int AUXU, int AUXX, int SCAT>
__global__ __launch_bounds__(512, 2) void hgemmB(
    int M, int N, int K,
    const f16* __restrict__ A, int lda,
    const f16* __restrict__ Bt,
    f16* __restrict__ C, int ldc,
    const float* __restrict__ bias,
    const f16* __restrict__ utab, const int* __restrict__ uidx,
    const float* __restrict__ x9, const int* __restrict__ xidx, const float* __restrict__ W9,
    float* __restrict__ sout, const int* __restrict__ sidx)
{
    __shared__ __align__(16) char Ash[2][2][16384];   // [dbuf][khalf][256 rows x 64B]
    __shared__ float Ws9[AUXX ? 2304 : 1];            // 9 x 256

    const int tid  = threadIdx.x;
    const int lane = tid & 63;
    const int w    = tid >> 6;

    // T1: bijective XCD-chunked remap (m204), bm-major
    const int nbn = gridDim.x;
    const int nwg = nbn * gridDim.y;
    int d  = blockIdx.y * nbn + blockIdx.x;
    int q8 = nwg >> 3, r8 = nwg & 7;
    int xk = d & 7, j8 = d >> 3;
    int wl = (xk < r8 ? xk * (q8 + 1) : r8 * (q8 + 1) + (xk - r8) * q8) + j8;
    const int bm = (wl / nbn) * 256;
    const int bn = (wl % nbn) * 256;

    const int wm = (w >> 2) * 128;
    const int wn = (w & 3) * 64;
    const int fr = lane & 15;
    const int kq = lane >> 4;

    const char* Ab = (const char*)A;
    const char* Bb = (const char*)Bt;
    const size_t lda2 = (size_t)lda * 2;
    const size_t ldb2 = (size_t)K * 2;

    f32x4 acc[8][4] = {};

    // a-frag ds_read offsets within a 16KB half-buffer (row=64B, slot swz s = kq ^ ((r>>1)&3))
    int aoff[8];
#pragma unroll
    for (int mi = 0; mi < 8; ++mi) {
        int r = wm + mi * 16 + fr;
        aoff[mi] = r * 64 + ((kq ^ ((r >> 1) & 3)) << 4);
    }

    // A staging: 2 halves x 16KB; 512 thr x 2 x 16B per half; pre-swizzled global source
    int sdest[2];
    size_t gsrcA[2];
#pragma unroll
    for (int i = 0; i < 2; ++i) {
        int Lo = i * 8192 + tid * 16;
        int row = Lo >> 6;
        int s = (Lo >> 4) & 3;
        int sw = (s ^ ((row >> 1) & 3)) << 4;
        sdest[i] = Lo;
        gsrcA[i] = (size_t)(bm + row) * lda2 + sw;
    }

    // B direct-load bases: lane reads 16B at row (bn+wn+ni*16+fr), kbyte kq*16 (+ks*64 + t*128)
    const char* bbase[4];
#pragma unroll
    for (int ni = 0; ni < 4; ++ni)
        bbase[ni] = Bb + (size_t)(bn + wn + ni * 16 + fr) * ldb2 + kq * 16;

    const int NT = K >> 6;

    auto stageA = [&](int t, int buf) {   // 4 gl_lds: both k-halves
        size_t kb = (size_t)t << 7;
#pragma unroll
        for (int h = 0; h < 2; ++h)
#pragma unroll
            for (int i = 0; i < 2; ++i)
                gl_lds16(Ab + gsrcA[i] + kb + h * 64, &Ash[buf][h][0] + sdest[i]);
    };
    auto loadB = [&](BF& dst, int t) {    // 8 global_load_dwordx4
        size_t kb = (size_t)t << 7;
#pragma unroll
        for (int ni = 0; ni < 4; ++ni)
#pragma unroll
            for (int ks = 0; ks < 2; ++ks)
                dst.v[ni][ks] = *(const f16x8*)(bbase[ni] + kb + ks * 64);
    };
    auto body = [&](int t, int buf, const BF& cur, BF& nxt) {
        const bool pre = (t + 1 < NT);
        if (pre) {
            stageA(t + 1, buf ^ 1);
            loadB(nxt, t + 1);
            SCHED0;
            VMW12;                         // tile t's 12 ops retired; t+1's in flight
        } else {
            VMW0;
        }
        SBAR;                              // A(t) visible block-wide
#pragma unroll
        for (int ks = 0; ks < 2; ++ks) {
            const char* half = &Ash[buf][ks][0];
#pragma unroll
            for (int g = 0; g < 2; ++g) {
                f16x8 a[4];
#pragma unroll
                for (int i = 0; i < 4; ++i) a[i] = *(const f16x8*)(half + aoff[g * 4 + i]);
                LGKM(0);
                __builtin_amdgcn_s_setprio(1);
#pragma unroll
                for (int mi = 0; mi < 4; ++mi)
#pragma unroll
                    for (int ni = 0; ni < 4; ++ni)
                        acc[g * 4 + mi][ni] = MFMA16(a[mi], cur.v[ni][ks], acc[g * 4 + mi][ni]);
                __builtin_amdgcn_s_setprio(0);
            }
        }
        SBAR;                              // all reads of buf done (WAR-safe restage)
    };

    BF bf0, bf1;
    stageA(0, 0);
    loadB(bf0, 0);
    int t = 0;
    for (; t + 2 <= NT; t += 2) {
        body(t,     0, bf0, bf1);
        body(t + 1, 1, bf1, bf0);
    }
    if (t < NT) body(t, t & 1, bf0, bf1);   // NT odd (e.g. NT=1)

    if (AUXX) {
        for (int i = tid; i < 9 * 256; i += 512)
            Ws9[i] = W9[(size_t)(i >> 8) * N + bn + (i & 255)];
        __syncthreads();
    }

    // C/D layout: col = lane&15, row = kq*4 + reg
#pragma unroll
    for (int mi = 0; mi < 8; ++mi) {
        int r0 = bm + wm + mi * 16 + kq * 4;
#pragma unroll
        for (int r = 0; r < 4; ++r) {
            int grow = r0 + r;
            if (grow >= M) continue;
            int ub = 0;
            if (AUXU) ub = uidx[grow];
            int sb = 0;
            if (SCAT) sb = sidx[grow];
            float xv[9];
            if (AUXX) {
                int xi = xidx ? xidx[grow] : grow;
#pragma unroll
                for (int q = 0; q < 9; ++q) xv[q] = x9[(size_t)xi * 9 + q];
            }
#pragma unroll
            for (int ni = 0; ni < 4; ++ni) {
                int lcol = wn + ni * 16 + fr;
                int col = bn + lcol;
                float v = acc[mi][ni][r] + bias[col];
                if (AUXU) v += (float)utab[(size_t)ub * N + col];
                if (AUXX) {
                    float s = 0.f;
#pragma unroll
                    for (int q = 0; q < 9; ++q) s = fmaf(xv[q], Ws9[q * 256 + lcol], s);
                    v += s;
                }
                if (RELU) v = fmaxf(v, 0.f);
                if (SCAT) {
                    atomicAdd(sout + (size_t)sb * N + col, v);
                } else {
                    C[(size_t)grow * ldc + col] = (f16)v;
                }
            }
        }
    }
}

// ---- merged weight prep ----
struct WtJob { const float* src; f16* dst; int r0, ks, n, kp, tr; };
struct WtJobs { WtJob j[10]; };

__global__ void k_wtall(WtJobs js)
{
    WtJob jb = js.j[blockIdx.y];
    size_t tot = (size_t)jb.n * jb.kp;
    size_t t = (size_t)blockIdx.x * 256 + threadIdx.x;
    if (t >= tot) return;
    if (jb.tr) {
        int n = (int)(t / jb.kp), k = (int)(t % jb.kp);
        jb.dst[t] = (k < jb.ks) ? (f16)jb.src[(size_t)(jb.r0 + k) * jb.n + n] : (f16)0.f;
    } else {
        jb.dst[t] = (f16)jb.src[t];
    }
}

__global__ void k_cbias(const float* __restrict__ n1W1, const float* __restrict__ eb5,
                        const float* __restrict__ n1b1, float* __restrict__ cb)
{
    int b = blockIdx.x * 256 + threadIdx.x;
    if (b >= 512) return;
    float s = n1b1[b];
    for (int c = 0; c < 512; ++c) s = fmaf(eb5[c], n1W1[(size_t)(9 + c) * 512 + b], s);
    cb[b] = s;
}

__global__ __launch_bounds__(256) void k_u2b(const float* __restrict__ u,
                                             const float* __restrict__ Wsel,
                                             const float* __restrict__ bsel,
                                             f16* __restrict__ u2h)
{
    __shared__ float us[4096];
    __shared__ float red[256];
    const int g = blockIdx.y;
    const int c0 = blockIdx.x * 16;
    const int col = threadIdx.x & 15;
    const int kp = threadIdx.x >> 4;
    for (int i = threadIdx.x; i < 4096; i += 256) us[i] = u[(size_t)g * 4096 + i];
    __syncthreads();
    float acc = 0.f;
    const float* wp = Wsel + (size_t)(kp * 256) * 256 + c0 + col;
#pragma unroll 8
    for (int i = 0; i < 256; ++i) acc = fmaf(us[kp * 256 + i], wp[(size_t)i * 256], acc);
    red[threadIdx.x] = acc;
    __syncthreads();
    if (kp < 8) red[threadIdx.x] += red[threadIdx.x + 128];
    __syncthreads();
    if (kp < 4) red[threadIdx.x] += red[threadIdx.x + 64];
    __syncthreads();
    if (kp < 2) red[threadIdx.x] += red[threadIdx.x + 32];
    __syncthreads();
    if (kp == 0)
        u2h[(size_t)g * 256 + c0 + col] = (f16)(red[threadIdx.x] + red[threadIdx.x + 16] + bsel[c0 + col]);
}

__global__ void k_gather19(const float* __restrict__ x, const float* __restrict__ eattr,
                           const int* __restrict__ ei, const int* __restrict__ batch,
                           f16* __restrict__ feat, int* __restrict__ ebat)
{
    size_t t = (size_t)blockIdx.x * 256 + threadIdx.x;
    if (t >= (size_t)E_TOTAL * 64) return;
    int i = (int)(t >> 6), j = (int)(t & 63);
    float v = 0.f;
    if (j < 9)        v = x[ei[i] * 9 + j];
    else if (j < 18)  v = x[ei[E_TOTAL + i] * 9 + (j - 9)];
    else if (j == 18) v = eattr[i];
    else if (j == 19) ebat[i] = batch[ei[i]];
    feat[t] = (f16)v;
}

__global__ void k_cnt(const int* __restrict__ ei, float* __restrict__ cnt)
{
    int t = blockIdx.x * 256 + threadIdx.x;
    if (t < E_TOTAL) atomicAdd(cnt + ei[t], 1.0f);
}

__global__ void k_agg(const float* __restrict__ ssum, const float* __restrict__ cnt,
                      f16* __restrict__ agg)
{
    size_t t = (size_t)blockIdx.x * 256 + threadIdx.x;
    if (t >= (size_t)NN * 512) return;
    int n = (int)(t >> 9);
    agg[t] = (f16)(ssum[t] / fmaxf(cnt[n], 1.f));
}

__global__ void k_final(const f16* __restrict__ z1, const float* __restrict__ W,
                        const float* __restrict__ b, float* __restrict__ out)
{
    int gt = blockIdx.x * 256 + threadIdx.x;
    int row = gt >> 6;
    int lane = threadIdx.x & 63;
    if (row >= NN) return;
    float s = 0.f;
#pragma unroll
    for (int c = lane; c < 512; c += 64) s += (float)z1[(size_t)row * 512 + c] * W[c];
#pragma unroll
    for (int off = 32; off; off >>= 1) s += __shfl_down(s, off);
    if (lane == 0) out[row] = s + b[0];
}

// ---------------- launch ----------------

extern "C" void kernel_launch(void* const* d_in, const int* in_sizes, int n_in,
                              void* d_out, int out_size, void* d_ws, size_t ws_size,
                              hipStream_t stream)
{
    const float* x     = (const float*)d_in[0];
    const float* eattr = (const float*)d_in[1];
    const float* u     = (const float*)d_in[2];
    const int*   ei    = (const int*)d_in[3];
    const int*   batch = (const int*)d_in[4];
    const float* Wsel  = (const float*)d_in[5];
    const float* bsel  = (const float*)d_in[6];
    const float* eW1 = (const float*)d_in[7],  * eb1 = (const float*)d_in[8];
    const float* eW2 = (const float*)d_in[9],  * eb2 = (const float*)d_in[10];
    const float* eW3 = (const float*)d_in[11], * eb3 = (const float*)d_in[12];
    const float* eW4 = (const float*)d_in[13], * eb4 = (const float*)d_in[14];
    const float* eW5 = (const float*)d_in[15], * eb5 = (const float*)d_in[16];
    const float* n1W1 = (const float*)d_in[17], * n1b1 = (const float*)d_in[18];
    const float* n1W2 = (const float*)d_in[19], * n1b2 = (const float*)d_in[20];
    const float* n2W1 = (const float*)d_in[21], * n2b1 = (const float*)d_in[22];
    const float* n2W2 = (const float*)d_in[23], * n2b2 = (const float*)d_in[24];
    float* out = (float*)d_out;

    char* ws = (char*)d_ws;
    size_t off = 0;
    auto alc = [&](size_t bytes) { char* p = ws + off; off += (bytes + 255) & ~(size_t)255; return p; };

    float* ssum  = (float*)alc((size_t)NN * 512 * 4);
    float* cnt   = (float*)alc((size_t)NN * 4);
    float* zbias = (float*)alc(1024 * 4);
    float* cbias = (float*)alc(512 * 4);
    f16* u2h     = (f16*)alc((size_t)256 * 256 * 2);
    f16* ubias_e = (f16*)alc((size_t)64 * 1024 * 2);
    f16* ubias_n = (f16*)alc((size_t)64 * 512 * 2);
    f16* eW1t19  = (f16*)alc((size_t)1024 * 64 * 2);
    f16* eW1ut   = (f16*)alc((size_t)1024 * 256 * 2);
    f16* eW2t    = (f16*)alc((size_t)1024 * 1024 * 2);
    f16* eW3t    = (f16*)alc((size_t)1024 * 1024 * 2);
    f16* eW4t    = (f16*)alc((size_t)1024 * 1024 * 2);
    f16* eW5h    = (f16*)alc((size_t)1024 * 512 * 2);
    f16* combo_t = (f16*)alc((size_t)512 * 1024 * 2);
    f16* n1W1et  = (f16*)alc((size_t)512 * 512 * 2);
    f16* n1W2t   = (f16*)alc((size_t)512 * 512 * 2);
    f16* n2W1et  = (f16*)alc((size_t)512 * 512 * 2);
    f16* n2W1ut  = (f16*)alc((size_t)512 * 256 * 2);
    f16* featAll = (f16*)alc((size_t)E_TOTAL * 64 * 2);
    int* ebatAll = (int*)alc((size_t)E_TOTAL * 4);
    size_t fixed = off;

    size_t per_edge = 4096;
    size_t need_ro = (size_t)20224 * 512 * 2 * 2;
    size_t avail = ws_size > fixed ? ws_size - fixed : 0;
    long long Cmax = (long long)(avail / per_edge);
    int C;
    if (Cmax >= E_TOTAL)      C = E_TOTAL;
    else if (Cmax >= 16384)   C = (int)((Cmax / 16384) * 16384);
    else                      C = (int)((Cmax / 256) * 256);
    if ((size_t)C * per_edge < need_ro)
        C = (int)(((need_ro + per_edge - 1) / per_edge + 255) / 256 * 256);

    f16* buf1 = (f16*)(ws + fixed);
    f16* buf2 = buf1 + (size_t)C * 1024;
    f16* agg  = (f16*)(ws + fixed);
    f16* z1   = agg + (size_t)20224 * 512;

    size_t zlen = (size_t)((char*)cbias - (char*)ssum) + 512 * 4;
    hipMemsetAsync(ssum, 0, zlen, stream);

    WtJobs js;
    js.j[0] = {eW1,  eW1t19, 0,   19,   1024, 64,   1};
    js.j[1] = {eW1,  eW1ut,  19,  256,  1024, 256,  1};
    js.j[2] = {eW2,  eW2t,   0,   1024, 1024, 1024, 1};
    js.j[3] = {eW3,  eW3t,   0,   1024, 1024, 1024, 1};
    js.j[4] = {eW4,  eW4t,   0,   1024, 1024, 1024, 1};
    js.j[5] = {n1W1, n1W1et, 9,   512,  512,  512,  1};
    js.j[6] = {n1W2, n1W2t,  0,   512,  512,  512,  1};
    js.j[7] = {n2W1, n2W1et, 9,   512,  512,  512,  1};
    js.j[8] = {n2W1, n2W1ut, 521, 256,  512,  256,  1};
    js.j[9] = {eW5,  eW5h,   0,   0,    1024, 512,  0};
    k_wtall<<<dim3(4096, 10), 256, 0, stream>>>(js);

    k_u2b<<<dim3(16, NGRAPH), 256, 0, stream>>>(u, Wsel, bsel, u2h);
    k_cnt<<<(E_TOTAL + 255) / 256, 256, 0, stream>>>(ei, cnt);
    k_cbias<<<2, 256, 0, stream>>>(n1W1, eb5, n1b1, cbias);
    k_gather19<<<(unsigned)(((size_t)E_TOTAL * 64 + 255) / 256), 256, 0, stream>>>(
        x, eattr, ei, batch, featAll, ebatAll);

    hgemmB<0,0,0,0><<<dim3(4, 1), 512, 0, stream>>>(64, 1024, 256, u2h, 256, eW1ut,
        ubias_e, 1024, eb1, nullptr, nullptr, nullptr, nullptr, nullptr, nullptr, nullptr);
    hgemmB<0,0,0,0><<<dim3(2, 1), 512, 0, stream>>>(64, 512, 256, u2h, 256, n2W1ut,
        ubias_n, 512, n2b1, nullptr, nullptr, nullptr, nullptr, nullptr, nullptr, nullptr);

    hgemmB<0,0,0,0><<<dim3(4, 2), 512, 0, stream>>>(512, 1024, 512, n1W1et, 512, eW5h,
        combo_t, 1024, zbias, nullptr, nullptr, nullptr, nullptr, nullptr, nullptr, nullptr);

    for (int e0 = 0; e0 < E_TOTAL; e0 += C) {
        int Ce = E_TOTAL - e0 < C ? E_TOTAL - e0 : C;
        int gy = (Ce + 255) / 256;

        hgemmB<1,1,0,0><<<dim3(4, gy), 512, 0, stream>>>(Ce, 1024, 64,
            featAll + (size_t)e0 * 64, 64, eW1t19,
            buf1, 1024, zbias, ubias_e, ebatAll + e0, nullptr, nullptr, nullptr, nullptr, nullptr);
        hgemmB<1,0,0,0><<<dim3(4, gy), 512, 0, stream>>>(Ce, 1024, 1024, buf1, 1024, eW2t,
            buf2, 1024, eb2, nullptr, nullptr, nullptr, nullptr, nullptr, nullptr, nullptr);
        hgemmB<1,0,0,0><<<dim3(4, gy), 512, 0, stream>>>(Ce, 1024, 1024, buf2, 1024, eW3t,
            buf1, 1024, eb3, nullptr, nullptr, nullptr, nullptr, nullptr, nullptr, nullptr);
        hgemmB<1,0,0,0><<<dim3(4, gy), 512, 0, stream>>>(Ce, 1024, 1024, buf1, 1024, eW4t,
            buf2, 1024, eb4, nullptr, nullptr, nullptr, nullptr, nullptr, nullptr, nullptr);

        hgemmB<1,0,1,0><<<dim3(2, gy), 512, 0, stream>>>(Ce, 512, 1024, buf2, 1024, combo_t,
            buf1, 512, cbias, nullptr, nullptr, x, ei + E_TOTAL + e0, n1W1, nullptr, nullptr);

        hgemmB<1,0,0,1><<<dim3(2, gy), 512, 0, stream>>>(Ce, 512, 512, buf1, 512, n1W2t,
            nullptr, 512, n1b2, nullptr, nullptr, nullptr, nullptr, nullptr, ssum, ei + e0);
    }

    k_agg<<<(unsigned)(((size_t)NN * 512 + 255) / 256), 256, 0, stream>>>(ssum, cnt, agg);
    hgemmB<1,1,1,0><<<dim3(2, 79), 512, 0, stream>>>(NN, 512, 512, agg, 512, n2W1et,
        z1, 512, zbias, ubias_n, batch, x, nullptr, n2W1, nullptr, nullptr);
    k_final<<<(NN * 64 + 255) / 256, 256, 0, stream>>>(z1, n2W2, n2b2, out);
}

// Round 12
// 2304.452 us; speedup vs baseline: 3.6045x; 1.7739x over previous
//
#include <hip/hip_runtime.h>

typedef _Float16 f16;
typedef __attribute__((ext_vector_type(8))) _Float16 f16x8;
typedef __attribute__((ext_vector_type(4))) float f32x4;

#define E_TOTAL 160000
#define NN 20000
#define NGRAPH 64

__device__ __forceinline__ void gl_lds16(const void* g, void* l) {
    __builtin_amdgcn_global_load_lds((const __attribute__((address_space(1))) void*)g,
                                     (__attribute__((address_space(3))) void*)l, 16, 0, 0);
}

#define MFMA16(a, b, c) __builtin_amdgcn_mfma_f32_16x16x32_f16((a), (b), (c), 0, 0, 0)

// ===== hgemmM: m97-style 128x128 tile, BK=64, 4 waves (2x2), 32KB single-buffer LDS ==========
// C[M,N] = act(A[M,lda] @ Bt[N,K]^T + bias [+aux]).  K mult of 64, N mult of 128.
// High-occupancy path (~3 blocks/CU): plain __syncthreads() drains; cross-block wave overlap
// hides stage latency (m114/m97 mechanism).  T1: bijective XCD-chunked remap, bm-major, so the
// N/128 blocks sharing an A-panel run on one XCD (A fetched once per L2).
// Rows are 128B (64 k): XOR swizzle byte ^= (row&7)<<4 (G4 fix), pre-swizzled global source.
template <int RELU, int AUXU, int AUXX, int SCAT>
__global__ __launch_bounds__(256) void hgemmM(
    int M, int N, int K,
    const f16* __restrict__ A, int lda,
    const f16* __restrict__ Bt,
    f16* __restrict__ C, int ldc,
    const float* __restrict__ bias,
    const f16* __restrict__ utab, const int* __restrict__ uidx,
    const float* __restrict__ x9, const int* __restrict__ xidx, const float* __restrict__ W9,
    float* __restrict__ sout, const int* __restrict__ sidx)
{
    __shared__ __align__(16) char Ash[16384];
    __shared__ __align__(16) char Bsh[16384];
    __shared__ float Ws9[AUXX ? 1152 : 1];   // 9 x 128

    const int tid  = threadIdx.x;
    const int lane = tid & 63;
    const int w    = tid >> 6;            // 0..3

    // T1: bijective XCD-chunked remap (m204), bm-major
    const int nbn = gridDim.x;
    const int nwg = nbn * gridDim.y;
    int d  = blockIdx.y * nbn + blockIdx.x;
    int q8 = nwg >> 3, r8 = nwg & 7;
    int xk = d & 7, j8 = d >> 3;
    int wl = (xk < r8 ? xk * (q8 + 1) : r8 * (q8 + 1) + (xk - r8) * q8) + j8;
    const int bm = (wl / nbn) * 128;
    const int bn = (wl % nbn) * 128;

    const int wm = (w >> 1) * 64;
    const int wn = (w & 1) * 64;
    const int fr = lane & 15;
    const int kq = lane >> 4;

    const char* Ab = (const char*)A;
    const char* Bb = (const char*)Bt;
    const size_t lda2 = (size_t)lda * 2;
    const size_t ldb2 = (size_t)K * 2;

    f32x4 acc[4][4] = {};

    // frag ds_read offsets: row r at r*128, byte c = ks*64 + kq*16, swizzle c ^= (r&7)<<4
    int aoff[4], boff[4];
#pragma unroll
    for (int mi = 0; mi < 4; ++mi) {
        int r = wm + mi * 16 + fr;
        aoff[mi] = r * 128 + ((kq * 16) ^ ((r & 7) << 4));
    }
#pragma unroll
    for (int ni = 0; ni < 4; ++ni) {
        int r = wn + ni * 16 + fr;
        boff[ni] = r * 128 + ((kq * 16) ^ ((r & 7) << 4));
    }

    // staging: 16KB per operand = 256 thr x 4 x 16B; linear LDS dest, pre-swizzled global src
    int sdest[4];
    size_t gsrcA[4], gsrcB[4];
#pragma unroll
    for (int i = 0; i < 4; ++i) {
        int L = i * 4096 + tid * 16;
        int row = L >> 7;
        int scb = (L & 127) ^ ((row & 7) << 4);
        sdest[i] = L;
        gsrcA[i] = (size_t)(bm + row) * lda2 + scb;
        gsrcB[i] = (size_t)(bn + row) * ldb2 + scb;
    }

    const int NT = K >> 6;

    for (int t = 0; t < NT; ++t) {
        size_t kb = (size_t)t << 7;
#pragma unroll
        for (int i = 0; i < 4; ++i) gl_lds16(Ab + gsrcA[i] + kb, Ash + sdest[i]);
#pragma unroll
        for (int i = 0; i < 4; ++i) gl_lds16(Bb + gsrcB[i] + kb, Bsh + sdest[i]);
        __syncthreads();                       // drains vmcnt(0): tile t in LDS
#pragma unroll
        for (int ks = 0; ks < 2; ++ks) {
            f16x8 a[4], b[4];
#pragma unroll
            for (int i = 0; i < 4; ++i) a[i] = *(const f16x8*)(Ash + (aoff[i] ^ (ks * 64)));
#pragma unroll
            for (int i = 0; i < 4; ++i) b[i] = *(const f16x8*)(Bsh + (boff[i] ^ (ks * 64)));
#pragma unroll
            for (int mi = 0; mi < 4; ++mi)
#pragma unroll
                for (int ni = 0; ni < 4; ++ni)
                    acc[mi][ni] = MFMA16(a[mi], b[ni], acc[mi][ni]);
        }
        __syncthreads();                       // all reads retired (WAR before next stage)
    }

    if (AUXX) {
        for (int i = tid; i < 9 * 128; i += 256)
            Ws9[i] = W9[(size_t)(i >> 7) * N + bn + (i & 127)];
        __syncthreads();
    }

    // C/D layout: col = lane&15, row = kq*4 + reg
#pragma unroll
    for (int mi = 0; mi < 4; ++mi) {
        int r0 = bm + wm + mi * 16 + kq * 4;
#pragma unroll
        for (int r = 0; r < 4; ++r) {
            int grow = r0 + r;
            if (grow >= M) continue;
            int ub = 0;
            if (AUXU) ub = uidx[grow];
            int sb = 0;
            if (SCAT) sb = sidx[grow];
            float xv[9];
            if (AUXX) {
                int xi = xidx ? xidx[grow] : grow;
#pragma unroll
                for (int q = 0; q < 9; ++q) xv[q] = x9[(size_t)xi * 9 + q];
            }
#pragma unroll
            for (int ni = 0; ni < 4; ++ni) {
                int lcol = wn + ni * 16 + fr;
                int col = bn + lcol;
                float v = acc[mi][ni][r] + bias[col];
                if (AUXU) v += (float)utab[(size_t)ub * N + col];
                if (AUXX) {
                    float s = 0.f;
#pragma unroll
                    for (int q = 0; q < 9; ++q) s = fmaf(xv[q], Ws9[q * 128 + lcol], s);
                    v += s;
                }
                if (RELU) v = fmaxf(v, 0.f);
                if (SCAT) {
                    atomicAdd(sout + (size_t)sb * N + col, v);
                } else {
                    C[(size_t)grow * ldc + col] = (f16)v;
                }
            }
        }
    }
}

// ---- merged weight prep ----
struct WtJob { const float* src; f16* dst; int r0, ks, n, kp, tr; };
struct WtJobs { WtJob j[10]; };

__global__ void k_wtall(WtJobs js)
{
    WtJob jb = js.j[blockIdx.y];
    size_t tot = (size_t)jb.n * jb.kp;
    size_t t = (size_t)blockIdx.x * 256 + threadIdx.x;
    if (t >= tot) return;
    if (jb.tr) {
        int n = (int)(t / jb.kp), k = (int)(t % jb.kp);
        jb.dst[t] = (k < jb.ks) ? (f16)jb.src[(size_t)(jb.r0 + k) * jb.n + n] : (f16)0.f;
    } else {
        jb.dst[t] = (f16)jb.src[t];
    }
}

__global__ void k_cbias(const float* __restrict__ n1W1, const float* __restrict__ eb5,
                        const float* __restrict__ n1b1, float* __restrict__ cb)
{
    int b = blockIdx.x * 256 + threadIdx.x;
    if (b >= 512) return;
    float s = n1b1[b];
    for (int c = 0; c < 512; ++c) s = fmaf(eb5[c], n1W1[(size_t)(9 + c) * 512 + b], s);
    cb[b] = s;
}

__global__ __launch_bounds__(256) void k_u2b(const float* __restrict__ u,
                                             const float* __restrict__ Wsel,
                                             const float* __restrict__ bsel,
                                             f16* __restrict__ u2h)
{
    __shared__ float us[4096];
    __shared__ float red[256];
    const int g = blockIdx.y;
    const int c0 = blockIdx.x * 16;
    const int col = threadIdx.x & 15;
    const int kp = threadIdx.x >> 4;
    for (int i = threadIdx.x; i < 4096; i += 256) us[i] = u[(size_t)g * 4096 + i];
    __syncthreads();
    float acc = 0.f;
    const float* wp = Wsel + (size_t)(kp * 256) * 256 + c0 + col;
#pragma unroll 8
    for (int i = 0; i < 256; ++i) acc = fmaf(us[kp * 256 + i], wp[(size_t)i * 256], acc);
    red[threadIdx.x] = acc;
    __syncthreads();
    if (kp < 8) red[threadIdx.x] += red[threadIdx.x + 128];
    __syncthreads();
    if (kp < 4) red[threadIdx.x] += red[threadIdx.x + 64];
    __syncthreads();
    if (kp < 2) red[threadIdx.x] += red[threadIdx.x + 32];
    __syncthreads();
    if (kp == 0)
        u2h[(size_t)g * 256 + c0 + col] = (f16)(red[threadIdx.x] + red[threadIdx.x + 16] + bsel[c0 + col]);
}

__global__ void k_gather19(const float* __restrict__ x, const float* __restrict__ eattr,
                           const int* __restrict__ ei, const int* __restrict__ batch,
                           f16* __restrict__ feat, int* __restrict__ ebat)
{
    size_t t = (size_t)blockIdx.x * 256 + threadIdx.x;
    if (t >= (size_t)E_TOTAL * 64) return;
    int i = (int)(t >> 6), j = (int)(t & 63);
    float v = 0.f;
    if (j < 9)        v = x[ei[i] * 9 + j];
    else if (j < 18)  v = x[ei[E_TOTAL + i] * 9 + (j - 9)];
    else if (j == 18) v = eattr[i];
    else if (j == 19) ebat[i] = batch[ei[i]];
    feat[t] = (f16)v;
}

__global__ void k_cnt(const int* __restrict__ ei, float* __restrict__ cnt)
{
    int t = blockIdx.x * 256 + threadIdx.x;
    if (t < E_TOTAL) atomicAdd(cnt + ei[t], 1.0f);
}

__global__ void k_agg(const float* __restrict__ ssum, const float* __restrict__ cnt,
                      f16* __restrict__ agg)
{
    size_t t = (size_t)blockIdx.x * 256 + threadIdx.x;
    if (t >= (size_t)NN * 512) return;
    int n = (int)(t >> 9);
    agg[t] = (f16)(ssum[t] / fmaxf(cnt[n], 1.f));
}

__global__ void k_final(const f16* __restrict__ z1, const float* __restrict__ W,
                        const float* __restrict__ b, float* __restrict__ out)
{
    int gt = blockIdx.x * 256 + threadIdx.x;
    int row = gt >> 6;
    int lane = threadIdx.x & 63;
    if (row >= NN) return;
    float s = 0.f;
#pragma unroll
    for (int c = lane; c < 512; c += 64) s += (float)z1[(size_t)row * 512 + c] * W[c];
#pragma unroll
    for (int off = 32; off; off >>= 1) s += __shfl_down(s, off);
    if (lane == 0) out[row] = s + b[0];
}

// ---------------- launch ----------------

extern "C" void kernel_launch(void* const* d_in, const int* in_sizes, int n_in,
                              void* d_out, int out_size, void* d_ws, size_t ws_size,
                              hipStream_t stream)
{
    const float* x     = (const float*)d_in[0];
    const float* eattr = (const float*)d_in[1];
    const float* u     = (const float*)d_in[2];
    const int*   ei    = (const int*)d_in[3];
    const int*   batch = (const int*)d_in[4];
    const float* Wsel  = (const float*)d_in[5];
    const float* bsel  = (const float*)d_in[6];
    const float* eW1 = (const float*)d_in[7],  * eb1 = (const float*)d_in[8];
    const float* eW2 = (const float*)d_in[9],  * eb2 = (const float*)d_in[10];
    const float* eW3 = (const float*)d_in[11], * eb3 = (const float*)d_in[12];
    const float* eW4 = (const float*)d_in[13], * eb4 = (const float*)d_in[14];
    const float* eW5 = (const float*)d_in[15], * eb5 = (const float*)d_in[16];
    const float* n1W1 = (const float*)d_in[17], * n1b1 = (const float*)d_in[18];
    const float* n1W2 = (const float*)d_in[19], * n1b2 = (const float*)d_in[20];
    const float* n2W1 = (const float*)d_in[21], * n2b1 = (const float*)d_in[22];
    const float* n2W2 = (const float*)d_in[23], * n2b2 = (const float*)d_in[24];
    float* out = (float*)d_out;

    char* ws = (char*)d_ws;
    size_t off = 0;
    auto alc = [&](size_t bytes) { char* p = ws + off; off += (bytes + 255) & ~(size_t)255; return p; };

    float* ssum  = (float*)alc((size_t)NN * 512 * 4);
    float* cnt   = (float*)alc((size_t)NN * 4);
    float* zbias = (float*)alc(1024 * 4);
    float* cbias = (float*)alc(512 * 4);
    f16* u2h     = (f16*)alc((size_t)256 * 256 * 2);
    f16* ubias_e = (f16*)alc((size_t)64 * 1024 * 2);
    f16* ubias_n = (f16*)alc((size_t)64 * 512 * 2);
    f16* eW1t19  = (f16*)alc((size_t)1024 * 64 * 2);
    f16* eW1ut   = (f16*)alc((size_t)1024 * 256 * 2);
    f16* eW2t    = (f16*)alc((size_t)1024 * 1024 * 2);
    f16* eW3t    = (f16*)alc((size_t)1024 * 1024 * 2);
    f16* eW4t    = (f16*)alc((size_t)1024 * 1024 * 2);
    f16* eW5h    = (f16*)alc((size_t)1024 * 512 * 2);
    f16* combo_t = (f16*)alc((size_t)512 * 1024 * 2);
    f16* n1W1et  = (f16*)alc((size_t)512 * 512 * 2);
    f16* n1W2t   = (f16*)alc((size_t)512 * 512 * 2);
    f16* n2W1et  = (f16*)alc((size_t)512 * 512 * 2);
    f16* n2W1ut  = (f16*)alc((size_t)512 * 256 * 2);
    f16* featAll = (f16*)alc((size_t)E_TOTAL * 64 * 2);
    int* ebatAll = (int*)alc((size_t)E_TOTAL * 4);
    size_t fixed = off;

    size_t per_edge = 4096;
    size_t need_ro = (size_t)20224 * 512 * 2 * 2;
    size_t avail = ws_size > fixed ? ws_size - fixed : 0;
    long long Cmax = (long long)(avail / per_edge);
    int C;
    if (Cmax >= E_TOTAL)      C = E_TOTAL;
    else if (Cmax >= 16384)   C = (int)((Cmax / 16384) * 16384);
    else                      C = (int)((Cmax / 256) * 256);
    if ((size_t)C * per_edge < need_ro)
        C = (int)(((need_ro + per_edge - 1) / per_edge + 255) / 256 * 256);

    f16* buf1 = (f16*)(ws + fixed);
    f16* buf2 = buf1 + (size_t)C * 1024;
    f16* agg  = (f16*)(ws + fixed);
    f16* z1   = agg + (size_t)20224 * 512;

    size_t zlen = (size_t)((char*)cbias - (char*)ssum) + 512 * 4;
    hipMemsetAsync(ssum, 0, zlen, stream);

    WtJobs js;
    js.j[0] = {eW1,  eW1t19, 0,   19,   1024, 64,   1};
    js.j[1] = {eW1,  eW1ut,  19,  256,  1024, 256,  1};
    js.j[2] = {eW2,  eW2t,   0,   1024, 1024, 1024, 1};
    js.j[3] = {eW3,  eW3t,   0,   1024, 1024, 1024, 1};
    js.j[4] = {eW4,  eW4t,   0,   1024, 1024, 1024, 1};
    js.j[5] = {n1W1, n1W1et, 9,   512,  512,  512,  1};
    js.j[6] = {n1W2, n1W2t,  0,   512,  512,  512,  1};
    js.j[7] = {n2W1, n2W1et, 9,   512,  512,  512,  1};
    js.j[8] = {n2W1, n2W1ut, 521, 256,  512,  256,  1};
    js.j[9] = {eW5,  eW5h,   0,   0,    1024, 512,  0};
    k_wtall<<<dim3(4096, 10), 256, 0, stream>>>(js);

    k_u2b<<<dim3(16, NGRAPH), 256, 0, stream>>>(u, Wsel, bsel, u2h);
    k_cnt<<<(E_TOTAL + 255) / 256, 256, 0, stream>>>(ei, cnt);
    k_cbias<<<2, 256, 0, stream>>>(n1W1, eb5, n1b1, cbias);
    k_gather19<<<(unsigned)(((size_t)E_TOTAL * 64 + 255) / 256), 256, 0, stream>>>(
        x, eattr, ei, batch, featAll, ebatAll);

    // u-contribution tables
    hgemmM<0,0,0,0><<<dim3(8, 1), 256, 0, stream>>>(64, 1024, 256, u2h, 256, eW1ut,
        ubias_e, 1024, eb1, nullptr, nullptr, nullptr, nullptr, nullptr, nullptr, nullptr);
    hgemmM<0,0,0,0><<<dim3(4, 1), 256, 0, stream>>>(64, 512, 256, u2h, 256, n2W1ut,
        ubias_n, 512, n2b1, nullptr, nullptr, nullptr, nullptr, nullptr, nullptr, nullptr);

    // combo_t[b][a] = sum_c n1W1[9+c][b] * eW5[a][c]
    hgemmM<0,0,0,0><<<dim3(8, 4), 256, 0, stream>>>(512, 1024, 512, n1W1et, 512, eW5h,
        combo_t, 1024, zbias, nullptr, nullptr, nullptr, nullptr, nullptr, nullptr, nullptr);

    for (int e0 = 0; e0 < E_TOTAL; e0 += C) {
        int Ce = E_TOTAL - e0 < C ? E_TOTAL - e0 : C;
        int gy = (Ce + 127) / 128;

        hgemmM<1,1,0,0><<<dim3(8, gy), 256, 0, stream>>>(Ce, 1024, 64,
            featAll + (size_t)e0 * 64, 64, eW1t19,
            buf1, 1024, zbias, ubias_e, ebatAll + e0, nullptr, nullptr, nullptr, nullptr, nullptr);
        hgemmM<1,0,0,0><<<dim3(8, gy), 256, 0, stream>>>(Ce, 1024, 1024, buf1, 1024, eW2t,
            buf2, 1024, eb2, nullptr, nullptr, nullptr, nullptr, nullptr, nullptr, nullptr);
        hgemmM<1,0,0,0><<<dim3(8, gy), 256, 0, stream>>>(Ce, 1024, 1024, buf2, 1024, eW3t,
            buf1, 1024, eb3, nullptr, nullptr, nullptr, nullptr, nullptr, nullptr, nullptr);
        hgemmM<1,0,0,0><<<dim3(8, gy), 256, 0, stream>>>(Ce, 1024, 1024, buf1, 1024, eW4t,
            buf2, 1024, eb4, nullptr, nullptr, nullptr, nullptr, nullptr, nullptr, nullptr);

        hgemmM<1,0,1,0><<<dim3(4, gy), 256, 0, stream>>>(Ce, 512, 1024, buf2, 1024, combo_t,
            buf1, 512, cbias, nullptr, nullptr, x, ei + E_TOTAL + e0, n1W1, nullptr, nullptr);

        hgemmM<1,0,0,1><<<dim3(4, gy), 256, 0, stream>>>(Ce, 512, 512, buf1, 512, n1W2t,
            nullptr, 512, n1b2, nullptr, nullptr, nullptr, nullptr, nullptr, ssum, ei + e0);
    }

    k_agg<<<(unsigned)(((size_t)NN * 512 + 255) / 256), 256, 0, stream>>>(ssum, cnt, agg);
    hgemmM<1,1,1,0><<<dim3(4, 157), 256, 0, stream>>>(NN, 512, 512, agg, 512, n2W1et,
        z1, 512, zbias, ubias_n, batch, x, nullptr, n2W1, nullptr, nullptr);
    k_final<<<(NN * 64 + 255) / 256, 256, 0, stream>>>(z1, n2W2, n2b2, out);
}

// Round 13
// 2171.020 us; speedup vs baseline: 3.8260x; 1.0615x over previous
//
#include <hip/hip_runtime.h>

typedef _Float16 f16;
typedef __attribute__((ext_vector_type(8))) _Float16 f16x8;
typedef __attribute__((ext_vector_type(4))) float f32x4;

#define E_TOTAL 160000
#define NN 20000
#define NGRAPH 64

__device__ __forceinline__ void gl_lds16(const void* g, void* l) {
    __builtin_amdgcn_global_load_lds((const __attribute__((address_space(1))) void*)g,
                                     (__attribute__((address_space(3))) void*)l, 16, 0, 0);
}

#define MFMA16(a, b, c) __builtin_amdgcn_mfma_f32_16x16x32_f16((a), (b), (c), 0, 0, 0)
#define LGKM(n) do { asm volatile("s_waitcnt lgkmcnt(" #n ")" ::: "memory"); \
                     __builtin_amdgcn_sched_barrier(0); } while (0)
#define VMW4  asm volatile("s_waitcnt vmcnt(4)" ::: "memory")
#define VMW0  asm volatile("s_waitcnt vmcnt(0)" ::: "memory")
#define SBAR  __builtin_amdgcn_s_barrier()
#define SCHED0 __builtin_amdgcn_sched_barrier(0)

// ------------- fp16 MFMA GEMM, 256x256, BK=64, 8 waves, pipelined-lgkm 4-phase, XCD swizzle ----
// (r9 kernel, best measured total; SCAT path removed from use)
template <int RELU, int AUXU, int AUXX>
__global__ __launch_bounds__(512, 2) void hgemm8(
    int M, int N, int K,
    const f16* __restrict__ A, int lda,
    const f16* __restrict__ Bt,
    f16* __restrict__ C, int ldc,
    const float* __restrict__ bias,
    const f16* __restrict__ utab, const int* __restrict__ uidx,
    const float* __restrict__ x9, const int* __restrict__ xidx, const float* __restrict__ W9)
{
    __shared__ __align__(16) char Ash[2][2][16384];
    __shared__ __align__(16) char Bsh[2][2][16384];
    __shared__ float Ws9[AUXX ? 2304 : 1];   // 9 x 256

    const int tid  = threadIdx.x;
    const int lane = tid & 63;
    const int w    = tid >> 6;

    // T1: bijective XCD-chunked remap (m204), bm-major
    const int nbn = gridDim.x;
    const int nwg = nbn * gridDim.y;
    int d  = blockIdx.y * nbn + blockIdx.x;
    int q8 = nwg >> 3, r8 = nwg & 7;
    int xk = d & 7, j8 = d >> 3;
    int wl = (xk < r8 ? xk * (q8 + 1) : r8 * (q8 + 1) + (xk - r8) * q8) + j8;
    const int bm = (wl / nbn) * 256;
    const int bn = (wl % nbn) * 256;

    const int wm = (w >> 2) * 128;
    const int wn = (w & 3) * 64;
    const int fr = lane & 15;
    const int kq = lane >> 4;

    const char* Ab = (const char*)A;
    const char* Bb = (const char*)Bt;
    const size_t lda2 = (size_t)lda * 2;
    const size_t ldb2 = (size_t)K * 2;

    f32x4 acc[8][4] = {};

    int aoff[8], boff[4];
#pragma unroll
    for (int mi = 0; mi < 8; ++mi) {
        int r = wm + mi * 16 + fr;
        aoff[mi] = r * 64 + ((kq ^ ((r >> 1) & 3)) << 4);
    }
#pragma unroll
    for (int ni = 0; ni < 4; ++ni) {
        int r = wn + ni * 16 + fr;
        boff[ni] = r * 64 + ((kq ^ ((r >> 1) & 3)) << 4);
    }

    int sdest[2];
    size_t gsrcA[2], gsrcB[2];
#pragma unroll
    for (int i = 0; i < 2; ++i) {
        int Lo = i * 8192 + tid * 16;
        int row = Lo >> 6;
        int s = (Lo >> 4) & 3;
        int sw = (s ^ ((row >> 1) & 3)) << 4;
        sdest[i] = Lo;
        gsrcA[i] = (size_t)(bm + row) * lda2 + sw;
        gsrcB[i] = (size_t)(bn + row) * ldb2 + sw;
    }

    const int NT = K >> 6;

    auto stageA = [&](int t, int h, int buf) {
        size_t kb = (size_t)t * 128 + h * 64;
#pragma unroll
        for (int i = 0; i < 2; ++i)
            gl_lds16(Ab + gsrcA[i] + kb, &Ash[buf][h][0] + sdest[i]);
    };
    auto stageB = [&](int t, int h, int buf) {
        size_t kb = (size_t)t * 128 + h * 64;
#pragma unroll
        for (int i = 0; i < 2; ++i)
            gl_lds16(Bb + gsrcB[i] + kb, &Bsh[buf][h][0] + sdest[i]);
    };

    f16x8 a0[4], b0[4], a1[4], a2[4], b2[4], a3[4];

    stageA(0, 0, 0); stageB(0, 0, 0); stageA(0, 1, 0); stageB(0, 1, 0);
    VMW4;
    SBAR;
#pragma unroll
    for (int i = 0; i < 4; ++i) a0[i] = *(const f16x8*)(&Ash[0][0][0] + aoff[i]);
#pragma unroll
    for (int i = 0; i < 4; ++i) b0[i] = *(const f16x8*)(&Bsh[0][0][0] + boff[i]);

    for (int t = 0; t < NT; ++t) {
        const int cur = t & 1, nxt = cur ^ 1;
        const bool pre = (t + 1 < NT);
        const char* A0 = &Ash[cur][0][0];
        const char* A1 = &Ash[cur][1][0];
        const char* B1 = &Bsh[cur][1][0];

#pragma unroll
        for (int i = 0; i < 4; ++i) a1[i] = *(const f16x8*)(A0 + aoff[4 + i]);
        if (pre) stageA(t + 1, 0, nxt);
        SBAR;
        LGKM(4);
        __builtin_amdgcn_s_setprio(1);
#pragma unroll
        for (int mi = 0; mi < 4; ++mi)
#pragma unroll
            for (int ni = 0; ni < 4; ++ni)
                acc[mi][ni] = MFMA16(a0[mi], b0[ni], acc[mi][ni]);
        __builtin_amdgcn_s_setprio(0);
        SBAR;

        if (pre) stageB(t + 1, 0, nxt);
        SBAR;
        LGKM(0);
        if (pre) { VMW4; } else { VMW0; }
        SBAR;
#pragma unroll
        for (int i = 0; i < 4; ++i) a2[i] = *(const f16x8*)(A1 + aoff[i]);
#pragma unroll
        for (int i = 0; i < 4; ++i) b2[i] = *(const f16x8*)(B1 + boff[i]);
        SCHED0;
        __builtin_amdgcn_s_setprio(1);
#pragma unroll
        for (int mi = 0; mi < 4; ++mi)
#pragma unroll
            for (int ni = 0; ni < 4; ++ni)
                acc[4 + mi][ni] = MFMA16(a1[mi], b0[ni], acc[4 + mi][ni]);
        __builtin_amdgcn_s_setprio(0);
        SBAR;

#pragma unroll
        for (int i = 0; i < 4; ++i) a3[i] = *(const f16x8*)(A1 + aoff[4 + i]);
        if (pre) stageA(t + 1, 1, nxt);
        SBAR;
        LGKM(4);
        __builtin_amdgcn_s_setprio(1);
#pragma unroll
        for (int mi = 0; mi < 4; ++mi)
#pragma unroll
            for (int ni = 0; ni < 4; ++ni)
                acc[mi][ni] = MFMA16(a2[mi], b2[ni], acc[mi][ni]);
        __builtin_amdgcn_s_setprio(0);
        SBAR;

        if (pre) stageB(t + 1, 1, nxt);
        SBAR;
        LGKM(0);
        if (pre) {
            VMW4;
            SBAR;
            const char* An = &Ash[nxt][0][0];
            const char* Bn = &Bsh[nxt][0][0];
#pragma unroll
            for (int i = 0; i < 4; ++i) a0[i] = *(const f16x8*)(An + aoff[i]);
#pragma unroll
            for (int i = 0; i < 4; ++i) b0[i] = *(const f16x8*)(Bn + boff[i]);
            SCHED0;
        }
        __builtin_amdgcn_s_setprio(1);
#pragma unroll
        for (int mi = 0; mi < 4; ++mi)
#pragma unroll
            for (int ni = 0; ni < 4; ++ni)
                acc[4 + mi][ni] = MFMA16(a3[mi], b2[ni], acc[4 + mi][ni]);
        __builtin_amdgcn_s_setprio(0);
        SBAR;
    }

    if (AUXX) {
        for (int i = tid; i < 9 * 256; i += 512)
            Ws9[i] = W9[(size_t)(i >> 8) * N + bn + (i & 255)];
        __syncthreads();
    }

    // C/D layout: col = lane&15, row = kq*4 + reg
#pragma unroll
    for (int mi = 0; mi < 8; ++mi) {
        int r0 = bm + wm + mi * 16 + kq * 4;
#pragma unroll
        for (int r = 0; r < 4; ++r) {
            int grow = r0 + r;
            if (grow >= M) continue;
            int ub = 0;
            if (AUXU) ub = uidx[grow];
            float xv[9];
            if (AUXX) {
                int xi = xidx ? xidx[grow] : grow;
#pragma unroll
                for (int q = 0; q < 9; ++q) xv[q] = x9[(size_t)xi * 9 + q];
            }
#pragma unroll
            for (int ni = 0; ni < 4; ++ni) {
                int lcol = wn + ni * 16 + fr;
                int col = bn + lcol;
                float v = acc[mi][ni][r] + bias[col];
                if (AUXU) v += (float)utab[(size_t)ub * N + col];
                if (AUXX) {
                    float s = 0.f;
#pragma unroll
                    for (int q = 0; q < 9; ++q) s = fmaf(xv[q], Ws9[q * 256 + lcol], s);
                    v += s;
                }
                if (RELU) v = fmaxf(v, 0.f);
                C[(size_t)grow * ldc + col] = (f16)v;
            }
        }
    }
}

// ---- merged weight prep ----
struct WtJob { const float* src; f16* dst; int r0, ks, n, kp, tr; };
struct WtJobs { WtJob j[10]; };

__global__ void k_wtall(WtJobs js)
{
    WtJob jb = js.j[blockIdx.y];
    size_t tot = (size_t)jb.n * jb.kp;
    size_t t = (size_t)blockIdx.x * 256 + threadIdx.x;
    if (t >= tot) return;
    if (jb.tr) {
        int n = (int)(t / jb.kp), k = (int)(t % jb.kp);
        jb.dst[t] = (k < jb.ks) ? (f16)jb.src[(size_t)(jb.r0 + k) * jb.n + n] : (f16)0.f;
    } else {
        jb.dst[t] = (f16)jb.src[t];
    }
}

__global__ void k_cbias(const float* __restrict__ n1W1, const float* __restrict__ eb5,
                        const float* __restrict__ n1b1, float* __restrict__ cb)
{
    int b = blockIdx.x * 256 + threadIdx.x;
    if (b >= 512) return;
    float s = n1b1[b];
    for (int c = 0; c < 512; ++c) s = fmaf(eb5[c], n1W1[(size_t)(9 + c) * 512 + b], s);
    cb[b] = s;
}

__global__ __launch_bounds__(256) void k_u2b(const float* __restrict__ u,
                                             const float* __restrict__ Wsel,
                                             const float* __restrict__ bsel,
                                             f16* __restrict__ u2h)
{
    __shared__ float us[4096];
    __shared__ float red[256];
    const int g = blockIdx.y;
    const int c0 = blockIdx.x * 16;
    const int col = threadIdx.x & 15;
    const int kp = threadIdx.x >> 4;
    for (int i = threadIdx.x; i < 4096; i += 256) us[i] = u[(size_t)g * 4096 + i];
    __syncthreads();
    float acc = 0.f;
    const float* wp = Wsel + (size_t)(kp * 256) * 256 + c0 + col;
#pragma unroll 8
    for (int i = 0; i < 256; ++i) acc = fmaf(us[kp * 256 + i], wp[(size_t)i * 256], acc);
    red[threadIdx.x] = acc;
    __syncthreads();
    if (kp < 8) red[threadIdx.x] += red[threadIdx.x + 128];
    __syncthreads();
    if (kp < 4) red[threadIdx.x] += red[threadIdx.x + 64];
    __syncthreads();
    if (kp < 2) red[threadIdx.x] += red[threadIdx.x + 32];
    __syncthreads();
    if (kp == 0)
        u2h[(size_t)g * 256 + c0 + col] = (f16)(red[threadIdx.x] + red[threadIdx.x + 16] + bsel[c0 + col]);
}

__global__ void k_cnt(const int* __restrict__ ei, float* __restrict__ cnt)
{
    int t = blockIdx.x * 256 + threadIdx.x;
    if (t < E_TOTAL) atomicAdd(cnt + ei[t], 1.0f);
}

// ---- exclusive scan of cnt (20000 f32 counts) -> offs[NN+1], cursor copy ----
__global__ __launch_bounds__(256) void k_scan(const float* __restrict__ cnt,
                                              int* __restrict__ offs, int* __restrict__ cursor)
{
    __shared__ int part[256];
    const int tid = threadIdx.x;
    const int n0 = tid * 79;                 // 256*79 = 20224 >= 20000
    int s = 0;
    for (int i = 0; i < 79; ++i) {
        int n = n0 + i;
        if (n < NN) s += (int)cnt[n];
    }
    part[tid] = s;
    __syncthreads();
    for (int dstep = 1; dstep < 256; dstep <<= 1) {
        int add = (tid >= dstep) ? part[tid - dstep] : 0;
        __syncthreads();
        part[tid] += add;
        __syncthreads();
    }
    int run = part[tid] - s;                 // exclusive prefix for this thread's range
    for (int i = 0; i < 79; ++i) {
        int n = n0 + i;
        if (n < NN) {
            offs[n] = run;
            cursor[n] = run;
            run += (int)cnt[n];
        }
    }
    if (tid == 255) offs[NN] = E_TOTAL;
}

// ---- perm[pos] = original edge index, sorted (counting-sort) by destination node ----
__global__ void k_perm(const int* __restrict__ ei, int* __restrict__ cursor,
                       int* __restrict__ perm)
{
    int e = blockIdx.x * 256 + threadIdx.x;
    if (e < E_TOTAL) {
        int pos = atomicAdd(cursor + ei[e], 1);
        perm[pos] = e;
    }
}

// ---- permuted per-edge gather: feat64, ebat (batch of row), colA (col node idx) ----
__global__ void k_gather19(const float* __restrict__ x, const float* __restrict__ eattr,
                           const int* __restrict__ ei, const int* __restrict__ batch,
                           const int* __restrict__ perm,
                           f16* __restrict__ feat, int* __restrict__ ebat, int* __restrict__ colA)
{
    size_t t = (size_t)blockIdx.x * 256 + threadIdx.x;
    if (t >= (size_t)E_TOTAL * 64) return;
    int j = (int)(t >> 6), jj = (int)(t & 63);
    int e = perm[j];
    float v = 0.f;
    if (jj < 9)        v = x[ei[e] * 9 + jj];
    else if (jj < 18)  v = x[ei[E_TOTAL + e] * 9 + (jj - 9)];
    else if (jj == 18) v = eattr[e];
    else if (jj == 19) ebat[j] = batch[ei[e]];
    else if (jj == 20) colA[j] = ei[E_TOTAL + e];
    feat[t] = (f16)v;
}

// ---- segmented sum of h2 rows (sorted by node) into ssum; non-atomic (kernels serialize) ----
__global__ void k_seg(int e0, int Ce, const f16* __restrict__ h2,
                      const int* __restrict__ offs, float* __restrict__ ssum)
{
    size_t t = (size_t)blockIdx.x * 256 + threadIdx.x;
    if (t >= (size_t)NN * 512) return;
    int n = (int)(t >> 9), col = (int)(t & 511);
    int lo = offs[n], hi = offs[n + 1];
    int e1 = e0 + Ce;
    if (lo < e0) lo = e0;
    if (hi > e1) hi = e1;
    if (lo >= hi) return;
    float s = 0.f;
    for (int j = lo; j < hi; ++j)
        s += (float)h2[(size_t)(j - e0) * 512 + col];
    ssum[t] += s;
}

__global__ void k_agg(const float* __restrict__ ssum, const float* __restrict__ cnt,
                      f16* __restrict__ agg)
{
    size_t t = (size_t)blockIdx.x * 256 + threadIdx.x;
    if (t >= (size_t)NN * 512) return;
    int n = (int)(t >> 9);
    agg[t] = (f16)(ssum[t] / fmaxf(cnt[n], 1.f));
}

__global__ void k_final(const f16* __restrict__ z1, const float* __restrict__ W,
                        const float* __restrict__ b, float* __restrict__ out)
{
    int gt = blockIdx.x * 256 + threadIdx.x;
    int row = gt >> 6;
    int lane = threadIdx.x & 63;
    if (row >= NN) return;
    float s = 0.f;
#pragma unroll
    for (int c = lane; c < 512; c += 64) s += (float)z1[(size_t)row * 512 + c] * W[c];
#pragma unroll
    for (int off = 32; off; off >>= 1) s += __shfl_down(s, off);
    if (lane == 0) out[row] = s + b[0];
}

// ---------------- launch ----------------

extern "C" void kernel_launch(void* const* d_in, const int* in_sizes, int n_in,
                              void* d_out, int out_size, void* d_ws, size_t ws_size,
                              hipStream_t stream)
{
    const float* x     = (const float*)d_in[0];
    const float* eattr = (const float*)d_in[1];
    const float* u     = (const float*)d_in[2];
    const int*   ei    = (const int*)d_in[3];
    const int*   batch = (const int*)d_in[4];
    const float* Wsel  = (const float*)d_in[5];
    const float* bsel  = (const float*)d_in[6];
    const float* eW1 = (const float*)d_in[7],  * eb1 = (const float*)d_in[8];
    const float* eW2 = (const float*)d_in[9],  * eb2 = (const float*)d_in[10];
    const float* eW3 = (const float*)d_in[11], * eb3 = (const float*)d_in[12];
    const float* eW4 = (const float*)d_in[13], * eb4 = (const float*)d_in[14];
    const float* eW5 = (const float*)d_in[15], * eb5 = (const float*)d_in[16];
    const float* n1W1 = (const float*)d_in[17], * n1b1 = (const float*)d_in[18];
    const float* n1W2 = (const float*)d_in[19], * n1b2 = (const float*)d_in[20];
    const float* n2W1 = (const float*)d_in[21], * n2b1 = (const float*)d_in[22];
    const float* n2W2 = (const float*)d_in[23], * n2b2 = (const float*)d_in[24];
    float* out = (float*)d_out;

    char* ws = (char*)d_ws;
    size_t off = 0;
    auto alc = [&](size_t bytes) { char* p = ws + off; off += (bytes + 255) & ~(size_t)255; return p; };

    float* ssum  = (float*)alc((size_t)NN * 512 * 4);
    float* cnt   = (float*)alc((size_t)NN * 4);
    float* zbias = (float*)alc(1024 * 4);
    float* cbias = (float*)alc(512 * 4);
    f16* u2h     = (f16*)alc((size_t)256 * 256 * 2);
    f16* ubias_e = (f16*)alc((size_t)64 * 1024 * 2);
    f16* ubias_n = (f16*)alc((size_t)64 * 512 * 2);
    f16* eW1t19  = (f16*)alc((size_t)1024 * 64 * 2);
    f16* eW1ut   = (f16*)alc((size_t)1024 * 256 * 2);
    f16* eW2t    = (f16*)alc((size_t)1024 * 1024 * 2);
    f16* eW3t    = (f16*)alc((size_t)1024 * 1024 * 2);
    f16* eW4t    = (f16*)alc((size_t)1024 * 1024 * 2);
    f16* eW5h    = (f16*)alc((size_t)1024 * 512 * 2);
    f16* combo_t = (f16*)alc((size_t)512 * 1024 * 2);
    f16* n1W1et  = (f16*)alc((size_t)512 * 512 * 2);
    f16* n1W2t   = (f16*)alc((size_t)512 * 512 * 2);
    f16* n2W1et  = (f16*)alc((size_t)512 * 512 * 2);
    f16* n2W1ut  = (f16*)alc((size_t)512 * 256 * 2);
    int* offs    = (int*)alc((size_t)(NN + 1) * 4);
    int* cursor  = (int*)alc((size_t)NN * 4);
    int* perm    = (int*)alc((size_t)E_TOTAL * 4);
    f16* featAll = (f16*)alc((size_t)E_TOTAL * 64 * 2);
    int* ebatAll = (int*)alc((size_t)E_TOTAL * 4);
    int* colAll  = (int*)alc((size_t)E_TOTAL * 4);
    size_t fixed = off;

    size_t per_edge = 4096;
    size_t need_ro = (size_t)20224 * 512 * 2 * 2;
    size_t avail = ws_size > fixed ? ws_size - fixed : 0;
    long long Cmax = (long long)(avail / per_edge);
    int C;
    if (Cmax >= E_TOTAL)      C = E_TOTAL;
    else if (Cmax >= 16384)   C = (int)((Cmax / 16384) * 16384);
    else                      C = (int)((Cmax / 256) * 256);
    if ((size_t)C * per_edge < need_ro)
        C = (int)(((need_ro + per_edge - 1) / per_edge + 255) / 256 * 256);

    f16* buf1 = (f16*)(ws + fixed);
    f16* buf2 = buf1 + (size_t)C * 1024;
    f16* agg  = (f16*)(ws + fixed);
    f16* z1   = agg + (size_t)20224 * 512;

    size_t zlen = (size_t)((char*)cbias - (char*)ssum) + 512 * 4;
    hipMemsetAsync(ssum, 0, zlen, stream);

    WtJobs js;
    js.j[0] = {eW1,  eW1t19, 0,   19,   1024, 64,   1};
    js.j[1] = {eW1,  eW1ut,  19,  256,  1024, 256,  1};
    js.j[2] = {eW2,  eW2t,   0,   1024, 1024, 1024, 1};
    js.j[3] = {eW3,  eW3t,   0,   1024, 1024, 1024, 1};
    js.j[4] = {eW4,  eW4t,   0,   1024, 1024, 1024, 1};
    js.j[5] = {n1W1, n1W1et, 9,   512,  512,  512,  1};
    js.j[6] = {n1W2, n1W2t,  0,   512,  512,  512,  1};
    js.j[7] = {n2W1, n2W1et, 9,   512,  512,  512,  1};
    js.j[8] = {n2W1, n2W1ut, 521, 256,  512,  256,  1};
    js.j[9] = {eW5,  eW5h,   0,   0,    1024, 512,  0};
    k_wtall<<<dim3(4096, 10), 256, 0, stream>>>(js);

    k_u2b<<<dim3(16, NGRAPH), 256, 0, stream>>>(u, Wsel, bsel, u2h);
    k_cnt<<<(E_TOTAL + 255) / 256, 256, 0, stream>>>(ei, cnt);
    k_scan<<<1, 256, 0, stream>>>(cnt, offs, cursor);
    k_perm<<<(E_TOTAL + 255) / 256, 256, 0, stream>>>(ei, cursor, perm);
    k_cbias<<<2, 256, 0, stream>>>(n1W1, eb5, n1b1, cbias);
    k_gather19<<<(unsigned)(((size_t)E_TOTAL * 64 + 255) / 256), 256, 0, stream>>>(
        x, eattr, ei, batch, perm, featAll, ebatAll, colAll);

    hgemm8<0,0,0><<<dim3(4, 1), 512, 0, stream>>>(64, 1024, 256, u2h, 256, eW1ut,
        ubias_e, 1024, eb1, nullptr, nullptr, nullptr, nullptr, nullptr);
    hgemm8<0,0,0><<<dim3(2, 1), 512, 0, stream>>>(64, 512, 256, u2h, 256, n2W1ut,
        ubias_n, 512, n2b1, nullptr, nullptr, nullptr, nullptr, nullptr);

    hgemm8<0,0,0><<<dim3(4, 2), 512, 0, stream>>>(512, 1024, 512, n1W1et, 512, eW5h,
        combo_t, 1024, zbias, nullptr, nullptr, nullptr, nullptr, nullptr);

    for (int e0 = 0; e0 < E_TOTAL; e0 += C) {
        int Ce = E_TOTAL - e0 < C ? E_TOTAL - e0 : C;
        int gy = (Ce + 255) / 256;

        hgemm8<1,1,0><<<dim3(4, gy), 512, 0, stream>>>(Ce, 1024, 64,
            featAll + (size_t)e0 * 64, 64, eW1t19,
            buf1, 1024, zbias, ubias_e, ebatAll + e0, nullptr, nullptr, nullptr);
        hgemm8<1,0,0><<<dim3(4, gy), 512, 0, stream>>>(Ce, 1024, 1024, buf1, 1024, eW2t,
            buf2, 1024, eb2, nullptr, nullptr, nullptr, nullptr, nullptr);
        hgemm8<1,0,0><<<dim3(4, gy), 512, 0, stream>>>(Ce, 1024, 1024, buf2, 1024, eW3t,
            buf1, 1024, eb3, nullptr, nullptr, nullptr, nullptr, nullptr);
        hgemm8<1,0,0><<<dim3(4, gy), 512, 0, stream>>>(Ce, 1024, 1024, buf1, 1024, eW4t,
            buf2, 1024, eb4, nullptr, nullptr, nullptr, nullptr, nullptr);

        // h1 = relu(x[col]@n1W1[0:9] + (buf2)@combo + cbias)
        hgemm8<1,0,1><<<dim3(2, gy), 512, 0, stream>>>(Ce, 512, 1024, buf2, 1024, combo_t,
            buf1, 512, cbias, nullptr, nullptr, x, colAll + e0, n1W1);

        // h2 = relu(h1@n1W2 + n1b2) -> buf2 (plain write, edges sorted by dest node)
        hgemm8<1,0,0><<<dim3(2, gy), 512, 0, stream>>>(Ce, 512, 512, buf1, 512, n1W2t,
            buf2, 512, n1b2, nullptr, nullptr, nullptr, nullptr, nullptr);

        // segmented sum into ssum (non-atomic; kernels on stream serialize)
        k_seg<<<(unsigned)(((size_t)NN * 512 + 255) / 256), 256, 0, stream>>>(
            e0, Ce, buf2, offs, ssum);
    }

    k_agg<<<(unsigned)(((size_t)NN * 512 + 255) / 256), 256, 0, stream>>>(ssum, cnt, agg);
    hgemm8<1,1,1><<<dim3(2, 79), 512, 0, stream>>>(NN, 512, 512, agg, 512, n2W1et,
        z1, 512, zbias, ubias_n, batch, x, nullptr, n2W1);
    k_final<<<(NN * 64 + 255) / 256, 256, 0, stream>>>(z1, n2W2, n2b2, out);
}

// Round 14
// 2160.931 us; speedup vs baseline: 3.8439x; 1.0047x over previous
//
#include <hip/hip_runtime.h>

typedef _Float16 f16;
typedef __attribute__((ext_vector_type(8))) _Float16 f16x8;
typedef __attribute__((ext_vector_type(4))) float f32x4;

#define E_TOTAL 160000
#define NN 20000
#define NGRAPH 64

__device__ __forceinline__ void gl_lds16(const void* g, void* l) {
    __builtin_amdgcn_global_load_lds((const __attribute__((address_space(1))) void*)g,
                                     (__attribute__((address_space(3))) void*)l, 16, 0, 0);
}

#define MFMA16(a, b, c) __builtin_amdgcn_mfma_f32_16x16x32_f16((a), (b), (c), 0, 0, 0)
#define LGKM(n) do { asm volatile("s_waitcnt lgkmcnt(" #n ")" ::: "memory"); \
                     __builtin_amdgcn_sched_barrier(0); } while (0)
#define VMW4  asm volatile("s_waitcnt vmcnt(4)" ::: "memory")
#define VMW0  asm volatile("s_waitcnt vmcnt(0)" ::: "memory")
#define SBAR  __builtin_amdgcn_s_barrier()
#define SCHED0 __builtin_amdgcn_sched_barrier(0)

// ------------- fp16 MFMA GEMM, 256x256, BK=64, 8 waves, pipelined-lgkm 4-phase, XCD swizzle ----
// (r9/r13 kernel, best measured; unchanged)
template <int RELU, int AUXU, int AUXX>
__global__ __launch_bounds__(512, 2) void hgemm8(
    int M, int N, int K,
    const f16* __restrict__ A, int lda,
    const f16* __restrict__ Bt,
    f16* __restrict__ C, int ldc,
    const float* __restrict__ bias,
    const f16* __restrict__ utab, const int* __restrict__ uidx,
    const float* __restrict__ x9, const int* __restrict__ xidx, const float* __restrict__ W9)
{
    __shared__ __align__(16) char Ash[2][2][16384];
    __shared__ __align__(16) char Bsh[2][2][16384];
    __shared__ float Ws9[AUXX ? 2304 : 1];   // 9 x 256

    const int tid  = threadIdx.x;
    const int lane = tid & 63;
    const int w    = tid >> 6;

    // T1: bijective XCD-chunked remap (m204), bm-major
    const int nbn = gridDim.x;
    const int nwg = nbn * gridDim.y;
    int d  = blockIdx.y * nbn + blockIdx.x;
    int q8 = nwg >> 3, r8 = nwg & 7;
    int xk = d & 7, j8 = d >> 3;
    int wl = (xk < r8 ? xk * (q8 + 1) : r8 * (q8 + 1) + (xk - r8) * q8) + j8;
    const int bm = (wl / nbn) * 256;
    const int bn = (wl % nbn) * 256;

    const int wm = (w >> 2) * 128;
    const int wn = (w & 3) * 64;
    const int fr = lane & 15;
    const int kq = lane >> 4;

    const char* Ab = (const char*)A;
    const char* Bb = (const char*)Bt;
    const size_t lda2 = (size_t)lda * 2;
    const size_t ldb2 = (size_t)K * 2;

    f32x4 acc[8][4] = {};

    int aoff[8], boff[4];
#pragma unroll
    for (int mi = 0; mi < 8; ++mi) {
        int r = wm + mi * 16 + fr;
        aoff[mi] = r * 64 + ((kq ^ ((r >> 1) & 3)) << 4);
    }
#pragma unroll
    for (int ni = 0; ni < 4; ++ni) {
        int r = wn + ni * 16 + fr;
        boff[ni] = r * 64 + ((kq ^ ((r >> 1) & 3)) << 4);
    }

    int sdest[2];
    size_t gsrcA[2], gsrcB[2];
#pragma unroll
    for (int i = 0; i < 2; ++i) {
        int Lo = i * 8192 + tid * 16;
        int row = Lo >> 6;
        int s = (Lo >> 4) & 3;
        int sw = (s ^ ((row >> 1) & 3)) << 4;
        sdest[i] = Lo;
        gsrcA[i] = (size_t)(bm + row) * lda2 + sw;
        gsrcB[i] = (size_t)(bn + row) * ldb2 + sw;
    }

    const int NT = K >> 6;

    auto stageA = [&](int t, int h, int buf) {
        size_t kb = (size_t)t * 128 + h * 64;
#pragma unroll
        for (int i = 0; i < 2; ++i)
            gl_lds16(Ab + gsrcA[i] + kb, &Ash[buf][h][0] + sdest[i]);
    };
    auto stageB = [&](int t, int h, int buf) {
        size_t kb = (size_t)t * 128 + h * 64;
#pragma unroll
        for (int i = 0; i < 2; ++i)
            gl_lds16(Bb + gsrcB[i] + kb, &Bsh[buf][h][0] + sdest[i]);
    };

    f16x8 a0[4], b0[4], a1[4], a2[4], b2[4], a3[4];

    stageA(0, 0, 0); stageB(0, 0, 0); stageA(0, 1, 0); stageB(0, 1, 0);
    VMW4;
    SBAR;
#pragma unroll
    for (int i = 0; i < 4; ++i) a0[i] = *(const f16x8*)(&Ash[0][0][0] + aoff[i]);
#pragma unroll
    for (int i = 0; i < 4; ++i) b0[i] = *(const f16x8*)(&Bsh[0][0][0] + boff[i]);

    for (int t = 0; t < NT; ++t) {
        const int cur = t & 1, nxt = cur ^ 1;
        const bool pre = (t + 1 < NT);
        const char* A0 = &Ash[cur][0][0];
        const char* A1 = &Ash[cur][1][0];
        const char* B1 = &Bsh[cur][1][0];

#pragma unroll
        for (int i = 0; i < 4; ++i) a1[i] = *(const f16x8*)(A0 + aoff[4 + i]);
        if (pre) stageA(t + 1, 0, nxt);
        SBAR;
        LGKM(4);
        __builtin_amdgcn_s_setprio(1);
#pragma unroll
        for (int mi = 0; mi < 4; ++mi)
#pragma unroll
            for (int ni = 0; ni < 4; ++ni)
                acc[mi][ni] = MFMA16(a0[mi], b0[ni], acc[mi][ni]);
        __builtin_amdgcn_s_setprio(0);
        SBAR;

        if (pre) stageB(t + 1, 0, nxt);
        SBAR;
        LGKM(0);
        if (pre) { VMW4; } else { VMW0; }
        SBAR;
#pragma unroll
        for (int i = 0; i < 4; ++i) a2[i] = *(const f16x8*)(A1 + aoff[i]);
#pragma unroll
        for (int i = 0; i < 4; ++i) b2[i] = *(const f16x8*)(B1 + boff[i]);
        SCHED0;
        __builtin_amdgcn_s_setprio(1);
#pragma unroll
        for (int mi = 0; mi < 4; ++mi)
#pragma unroll
            for (int ni = 0; ni < 4; ++ni)
                acc[4 + mi][ni] = MFMA16(a1[mi], b0[ni], acc[4 + mi][ni]);
        __builtin_amdgcn_s_setprio(0);
        SBAR;

#pragma unroll
        for (int i = 0; i < 4; ++i) a3[i] = *(const f16x8*)(A1 + aoff[4 + i]);
        if (pre) stageA(t + 1, 1, nxt);
        SBAR;
        LGKM(4);
        __builtin_amdgcn_s_setprio(1);
#pragma unroll
        for (int mi = 0; mi < 4; ++mi)
#pragma unroll
            for (int ni = 0; ni < 4; ++ni)
                acc[mi][ni] = MFMA16(a2[mi], b2[ni], acc[mi][ni]);
        __builtin_amdgcn_s_setprio(0);
        SBAR;

        if (pre) stageB(t + 1, 1, nxt);
        SBAR;
        LGKM(0);
        if (pre) {
            VMW4;
            SBAR;
            const char* An = &Ash[nxt][0][0];
            const char* Bn = &Bsh[nxt][0][0];
#pragma unroll
            for (int i = 0; i < 4; ++i) a0[i] = *(const f16x8*)(An + aoff[i]);
#pragma unroll
            for (int i = 0; i < 4; ++i) b0[i] = *(const f16x8*)(Bn + boff[i]);
            SCHED0;
        }
        __builtin_amdgcn_s_setprio(1);
#pragma unroll
        for (int mi = 0; mi < 4; ++mi)
#pragma unroll
            for (int ni = 0; ni < 4; ++ni)
                acc[4 + mi][ni] = MFMA16(a3[mi], b2[ni], acc[4 + mi][ni]);
        __builtin_amdgcn_s_setprio(0);
        SBAR;
    }

    if (AUXX) {
        for (int i = tid; i < 9 * 256; i += 512)
            Ws9[i] = W9[(size_t)(i >> 8) * N + bn + (i & 255)];
        __syncthreads();
    }

    // C/D layout: col = lane&15, row = kq*4 + reg
#pragma unroll
    for (int mi = 0; mi < 8; ++mi) {
        int r0 = bm + wm + mi * 16 + kq * 4;
#pragma unroll
        for (int r = 0; r < 4; ++r) {
            int grow = r0 + r;
            if (grow >= M) continue;
            int ub = 0;
            if (AUXU) ub = uidx[grow];
            float xv[9];
            if (AUXX) {
                int xi = xidx ? xidx[grow] : grow;
#pragma unroll
                for (int q = 0; q < 9; ++q) xv[q] = x9[(size_t)xi * 9 + q];
            }
#pragma unroll
            for (int ni = 0; ni < 4; ++ni) {
                int lcol = wn + ni * 16 + fr;
                int col = bn + lcol;
                float v = acc[mi][ni][r] + bias[col];
                if (AUXU) v += (float)utab[(size_t)ub * N + col];
                if (AUXX) {
                    float s = 0.f;
#pragma unroll
                    for (int q = 0; q < 9; ++q) s = fmaf(xv[q], Ws9[q * 256 + lcol], s);
                    v += s;
                }
                if (RELU) v = fmaxf(v, 0.f);
                C[(size_t)grow * ldc + col] = (f16)v;
            }
        }
    }
}

// ---- coalesced weight transpose: Wt[n][k] = W[(r0+k)*N + n], LDS 32x32 tiles ----
struct WtJob { const float* src; f16* dst; int r0, ks, n, kp; };
struct WtJobs { WtJob j[9]; };

__global__ __launch_bounds__(256) void k_wtt(WtJobs js)
{
    __shared__ f16 tile[32][33];
    WtJob jb = js.j[blockIdx.y];
    int tilesX = (jb.kp + 31) >> 5;
    int tilesY = (jb.n + 31) >> 5;
    int tl = blockIdx.x;
    if (tl >= tilesX * tilesY) return;
    int k0 = (tl % tilesX) << 5;
    int n0 = (tl / tilesX) << 5;
    int tx = threadIdx.x & 31, ty = threadIdx.x >> 5;
#pragma unroll
    for (int i = 0; i < 4; ++i) {
        int k = k0 + ty + i * 8;
        int n = n0 + tx;
        float v = (k < jb.ks && n < jb.n) ? jb.src[(size_t)(jb.r0 + k) * jb.n + n] : 0.f;
        tile[ty + i * 8][tx] = (f16)v;      // tile[k_local][n_local]
    }
    __syncthreads();
#pragma unroll
    for (int i = 0; i < 4; ++i) {
        int n = n0 + ty + i * 8;
        int k = k0 + tx;
        if (n < jb.n && k < jb.kp)
            jb.dst[(size_t)n * jb.kp + k] = tile[tx][ty + i * 8];
    }
}

// ---- plain f32 -> f16 copy (eW5) ----
__global__ void k_cvt(const float* __restrict__ W, f16* __restrict__ Wt, int n)
{
    int t = blockIdx.x * 256 + threadIdx.x;
    if (t < n) Wt[t] = (f16)W[t];
}

__global__ void k_cbias(const float* __restrict__ n1W1, const float* __restrict__ eb5,
                        const float* __restrict__ n1b1, float* __restrict__ cb)
{
    int b = blockIdx.x * 256 + threadIdx.x;
    if (b >= 512) return;
    float s = n1b1[b];
    for (int c = 0; c < 512; ++c) s = fmaf(eb5[c], n1W1[(size_t)(9 + c) * 512 + b], s);
    cb[b] = s;
}

__global__ __launch_bounds__(256) void k_u2b(const float* __restrict__ u,
                                             const float* __restrict__ Wsel,
                                             const float* __restrict__ bsel,
                                             f16* __restrict__ u2h)
{
    __shared__ float us[4096];
    __shared__ float red[256];
    const int g = blockIdx.y;
    const int c0 = blockIdx.x * 16;
    const int col = threadIdx.x & 15;
    const int kp = threadIdx.x >> 4;
    for (int i = threadIdx.x; i < 4096; i += 256) us[i] = u[(size_t)g * 4096 + i];
    __syncthreads();
    float acc = 0.f;
    const float* wp = Wsel + (size_t)(kp * 256) * 256 + c0 + col;
#pragma unroll 8
    for (int i = 0; i < 256; ++i) acc = fmaf(us[kp * 256 + i], wp[(size_t)i * 256], acc);
    red[threadIdx.x] = acc;
    __syncthreads();
    if (kp < 8) red[threadIdx.x] += red[threadIdx.x + 128];
    __syncthreads();
    if (kp < 4) red[threadIdx.x] += red[threadIdx.x + 64];
    __syncthreads();
    if (kp < 2) red[threadIdx.x] += red[threadIdx.x + 32];
    __syncthreads();
    if (kp == 0)
        u2h[(size_t)g * 256 + c0 + col] = (f16)(red[threadIdx.x] + red[threadIdx.x + 16] + bsel[c0 + col]);
}

__global__ void k_cnt(const int* __restrict__ ei, float* __restrict__ cnt)
{
    int t = blockIdx.x * 256 + threadIdx.x;
    if (t < E_TOTAL) atomicAdd(cnt + ei[t], 1.0f);
}

// ---- exclusive scan of cnt -> offs[NN+1], cursor copy ----
__global__ __launch_bounds__(256) void k_scan(const float* __restrict__ cnt,
                                              int* __restrict__ offs, int* __restrict__ cursor)
{
    __shared__ int part[256];
    const int tid = threadIdx.x;
    const int n0 = tid * 79;
    int s = 0;
    for (int i = 0; i < 79; ++i) {
        int n = n0 + i;
        if (n < NN) s += (int)cnt[n];
    }
    part[tid] = s;
    __syncthreads();
    for (int dstep = 1; dstep < 256; dstep <<= 1) {
        int add = (tid >= dstep) ? part[tid - dstep] : 0;
        __syncthreads();
        part[tid] += add;
        __syncthreads();
    }
    int run = part[tid] - s;
    for (int i = 0; i < 79; ++i) {
        int n = n0 + i;
        if (n < NN) {
            offs[n] = run;
            cursor[n] = run;
            run += (int)cnt[n];
        }
    }
    if (tid == 255) offs[NN] = E_TOTAL;
}

__global__ void k_perm(const int* __restrict__ ei, int* __restrict__ cursor,
                       int* __restrict__ perm)
{
    int e = blockIdx.x * 256 + threadIdx.x;
    if (e < E_TOTAL) {
        int pos = atomicAdd(cursor + ei[e], 1);
        perm[pos] = e;
    }
}

__global__ void k_gather19(const float* __restrict__ x, const float* __restrict__ eattr,
                           const int* __restrict__ ei, const int* __restrict__ batch,
                           const int* __restrict__ perm,
                           f16* __restrict__ feat, int* __restrict__ ebat, int* __restrict__ colA)
{
    size_t t = (size_t)blockIdx.x * 256 + threadIdx.x;
    if (t >= (size_t)E_TOTAL * 64) return;
    int j = (int)(t >> 6), jj = (int)(t & 63);
    int e = perm[j];
    float v = 0.f;
    if (jj < 9)        v = x[ei[e] * 9 + jj];
    else if (jj < 18)  v = x[ei[E_TOTAL + e] * 9 + (jj - 9)];
    else if (jj == 18) v = eattr[e];
    else if (jj == 19) ebat[j] = batch[ei[e]];
    else if (jj == 20) colA[j] = ei[E_TOTAL + e];
    feat[t] = (f16)v;
}

// ---- segmented sum of sorted h2 rows into ssum; FIRST: overwrite; LAST: emit agg ----
template <int FIRST, int LAST>
__global__ void k_seg(int e0, int Ce, const f16* __restrict__ h2,
                      const int* __restrict__ offs, float* __restrict__ ssum,
                      f16* __restrict__ agg)
{
    size_t t = (size_t)blockIdx.x * 256 + threadIdx.x;
    if (t >= (size_t)NN * 512) return;
    int n = (int)(t >> 9), col = (int)(t & 511);
    int lo0 = offs[n], hi0 = offs[n + 1];
    int lo = lo0, hi = hi0;
    int e1 = e0 + Ce;
    if (lo < e0) lo = e0;
    if (hi > e1) hi = e1;
    float s = 0.f;
    for (int j = lo; j < hi; ++j)
        s += (float)h2[(size_t)(j - e0) * 512 + col];
    if (LAST) {
        float tot = (FIRST ? 0.f : ssum[t]) + s;
        agg[t] = (f16)(tot / fmaxf((float)(hi0 - lo0), 1.f));
    } else if (FIRST) {
        ssum[t] = s;
    } else if (lo < hi) {
        ssum[t] += s;
    }
}

__global__ void k_final(const f16* __restrict__ z1, const float* __restrict__ W,
                        const float* __restrict__ b, float* __restrict__ out)
{
    int gt = blockIdx.x * 256 + threadIdx.x;
    int row = gt >> 6;
    int lane = threadIdx.x & 63;
    if (row >= NN) return;
    float s = 0.f;
#pragma unroll
    for (int c = lane; c < 512; c += 64) s += (float)z1[(size_t)row * 512 + c] * W[c];
#pragma unroll
    for (int off = 32; off; off >>= 1) s += __shfl_down(s, off);
    if (lane == 0) out[row] = s + b[0];
}

// ---------------- launch ----------------

extern "C" void kernel_launch(void* const* d_in, const int* in_sizes, int n_in,
                              void* d_out, int out_size, void* d_ws, size_t ws_size,
                              hipStream_t stream)
{
    const float* x     = (const float*)d_in[0];
    const float* eattr = (const float*)d_in[1];
    const float* u     = (const float*)d_in[2];
    const int*   ei    = (const int*)d_in[3];
    const int*   batch = (const int*)d_in[4];
    const float* Wsel  = (const float*)d_in[5];
    const float* bsel  = (const float*)d_in[6];
    const float* eW1 = (const float*)d_in[7],  * eb1 = (const float*)d_in[8];
    const float* eW2 = (const float*)d_in[9],  * eb2 = (const float*)d_in[10];
    const float* eW3 = (const float*)d_in[11], * eb3 = (const float*)d_in[12];
    const float* eW4 = (const float*)d_in[13], * eb4 = (const float*)d_in[14];
    const float* eW5 = (const float*)d_in[15], * eb5 = (const float*)d_in[16];
    const float* n1W1 = (const float*)d_in[17], * n1b1 = (const float*)d_in[18];
    const float* n1W2 = (const float*)d_in[19], * n1b2 = (const float*)d_in[20];
    const float* n2W1 = (const float*)d_in[21], * n2b1 = (const float*)d_in[22];
    const float* n2W2 = (const float*)d_in[23], * n2b2 = (const float*)d_in[24];
    float* out = (float*)d_out;

    char* ws = (char*)d_ws;
    size_t off = 0;
    auto alc = [&](size_t bytes) { char* p = ws + off; off += (bytes + 255) & ~(size_t)255; return p; };

    float* ssum  = (float*)alc((size_t)NN * 512 * 4);
    float* cnt   = (float*)alc((size_t)NN * 4);
    float* zbias = (float*)alc(1024 * 4);
    float* cbias = (float*)alc(512 * 4);
    f16* u2h     = (f16*)alc((size_t)256 * 256 * 2);
    f16* ubias_e = (f16*)alc((size_t)64 * 1024 * 2);
    f16* ubias_n = (f16*)alc((size_t)64 * 512 * 2);
    f16* eW1t19  = (f16*)alc((size_t)1024 * 64 * 2);
    f16* eW1ut   = (f16*)alc((size_t)1024 * 256 * 2);
    f16* eW2t    = (f16*)alc((size_t)1024 * 1024 * 2);
    f16* eW3t    = (f16*)alc((size_t)1024 * 1024 * 2);
    f16* eW4t    = (f16*)alc((size_t)1024 * 1024 * 2);
    f16* eW5h    = (f16*)alc((size_t)1024 * 512 * 2);
    f16* combo_t = (f16*)alc((size_t)512 * 1024 * 2);
    f16* n1W1et  = (f16*)alc((size_t)512 * 512 * 2);
    f16* n1W2t   = (f16*)alc((size_t)512 * 512 * 2);
    f16* n2W1et  = (f16*)alc((size_t)512 * 512 * 2);
    f16* n2W1ut  = (f16*)alc((size_t)512 * 256 * 2);
    int* offs    = (int*)alc((size_t)(NN + 1) * 4);
    int* cursor  = (int*)alc((size_t)NN * 4);
    int* perm    = (int*)alc((size_t)E_TOTAL * 4);
    f16* featAll = (f16*)alc((size_t)E_TOTAL * 64 * 2);
    int* ebatAll = (int*)alc((size_t)E_TOTAL * 4);
    int* colAll  = (int*)alc((size_t)E_TOTAL * 4);
    size_t fixed = off;

    size_t per_edge = 4096;
    size_t need_ro = (size_t)20224 * 512 * 2 * 2;
    size_t avail = ws_size > fixed ? ws_size - fixed : 0;
    long long Cmax = (long long)(avail / per_edge);
    int C;
    if (Cmax >= E_TOTAL)      C = E_TOTAL;
    else if (Cmax >= 16384)   C = (int)((Cmax / 16384) * 16384);
    else                      C = (int)((Cmax / 256) * 256);
    if ((size_t)C * per_edge < need_ro)
        C = (int)(((need_ro + per_edge - 1) / per_edge + 255) / 256 * 256);

    f16* buf1 = (f16*)(ws + fixed);
    f16* buf2 = buf1 + (size_t)C * 1024;
    f16* agg  = (f16*)(ws + fixed);            // alias over buf1 (written by last k_seg)
    f16* z1   = agg + (size_t)20224 * 512;

    // zero only cnt + zbias (ssum now written by k_seg<FIRST>; cbias fully written by k_cbias)
    size_t zlen = (size_t)((char*)zbias - (char*)cnt) + 1024 * 4;
    hipMemsetAsync(cnt, 0, zlen, stream);

    WtJobs js;
    js.j[0] = {eW1,  eW1t19, 0,   19,   1024, 64};
    js.j[1] = {eW1,  eW1ut,  19,  256,  1024, 256};
    js.j[2] = {eW2,  eW2t,   0,   1024, 1024, 1024};
    js.j[3] = {eW3,  eW3t,   0,   1024, 1024, 1024};
    js.j[4] = {eW4,  eW4t,   0,   1024, 1024, 1024};
    js.j[5] = {n1W1, n1W1et, 9,   512,  512,  512};
    js.j[6] = {n1W2, n1W2t,  0,   512,  512,  512};
    js.j[7] = {n2W1, n2W1et, 9,   512,  512,  512};
    js.j[8] = {n2W1, n2W1ut, 521, 256,  512,  256};
    k_wtt<<<dim3(1024, 9), 256, 0, stream>>>(js);        // max tiles: 32x32 = 1024 (eW2/3/4)
    k_cvt<<<(1024 * 512 + 255) / 256, 256, 0, stream>>>(eW5, eW5h, 1024 * 512);

    k_u2b<<<dim3(16, NGRAPH), 256, 0, stream>>>(u, Wsel, bsel, u2h);
    k_cnt<<<(E_TOTAL + 255) / 256, 256, 0, stream>>>(ei, cnt);
    k_scan<<<1, 256, 0, stream>>>(cnt, offs, cursor);
    k_perm<<<(E_TOTAL + 255) / 256, 256, 0, stream>>>(ei, cursor, perm);
    k_cbias<<<2, 256, 0, stream>>>(n1W1, eb5, n1b1, cbias);
    k_gather19<<<(unsigned)(((size_t)E_TOTAL * 64 + 255) / 256), 256, 0, stream>>>(
        x, eattr, ei, batch, perm, featAll, ebatAll, colAll);

    hgemm8<0,0,0><<<dim3(4, 1), 512, 0, stream>>>(64, 1024, 256, u2h, 256, eW1ut,
        ubias_e, 1024, eb1, nullptr, nullptr, nullptr, nullptr, nullptr);
    hgemm8<0,0,0><<<dim3(2, 1), 512, 0, stream>>>(64, 512, 256, u2h, 256, n2W1ut,
        ubias_n, 512, n2b1, nullptr, nullptr, nullptr, nullptr, nullptr);

    hgemm8<0,0,0><<<dim3(4, 2), 512, 0, stream>>>(512, 1024, 512, n1W1et, 512, eW5h,
        combo_t, 1024, zbias, nullptr, nullptr, nullptr, nullptr, nullptr);

    for (int e0 = 0; e0 < E_TOTAL; e0 += C) {
        int Ce = E_TOTAL - e0 < C ? E_TOTAL - e0 : C;
        int gy = (Ce + 255) / 256;
        bool first = (e0 == 0);
        bool last  = (e0 + Ce >= E_TOTAL);

        hgemm8<1,1,0><<<dim3(4, gy), 512, 0, stream>>>(Ce, 1024, 64,
            featAll + (size_t)e0 * 64, 64, eW1t19,
            buf1, 1024, zbias, ubias_e, ebatAll + e0, nullptr, nullptr, nullptr);
        hgemm8<1,0,0><<<dim3(4, gy), 512, 0, stream>>>(Ce, 1024, 1024, buf1, 1024, eW2t,
            buf2, 1024, eb2, nullptr, nullptr, nullptr, nullptr, nullptr);
        hgemm8<1,0,0><<<dim3(4, gy), 512, 0, stream>>>(Ce, 1024, 1024, buf2, 1024, eW3t,
            buf1, 1024, eb3, nullptr, nullptr, nullptr, nullptr, nullptr);
        hgemm8<1,0,0><<<dim3(4, gy), 512, 0, stream>>>(Ce, 1024, 1024, buf1, 1024, eW4t,
            buf2, 1024, eb4, nullptr, nullptr, nullptr, nullptr, nullptr);

        // h1 = relu(x[col]@n1W1[0:9] + (buf2)@combo + cbias)
        hgemm8<1,0,1><<<dim3(2, gy), 512, 0, stream>>>(Ce, 512, 1024, buf2, 1024, combo_t,
            buf1, 512, cbias, nullptr, nullptr, x, colAll + e0, n1W1);

        // h2 = relu(h1@n1W2 + n1b2) -> buf2 (plain write; edges sorted by dest node)
        hgemm8<1,0,0><<<dim3(2, gy), 512, 0, stream>>>(Ce, 512, 512, buf1, 512, n1W2t,
            buf2, 512, n1b2, nullptr, nullptr, nullptr, nullptr, nullptr);

        // segmented sum into ssum; last chunk also emits agg = mean (folds k_agg)
        unsigned sgrid = (unsigned)(((size_t)NN * 512 + 255) / 256);
        if (first && last)
            k_seg<1,1><<<sgrid, 256, 0, stream>>>(e0, Ce, buf2, offs, ssum, agg);
        else if (first)
            k_seg<1,0><<<sgrid, 256, 0, stream>>>(e0, Ce, buf2, offs, ssum, agg);
        else if (last)
            k_seg<0,1><<<sgrid, 256, 0, stream>>>(e0, Ce, buf2, offs, ssum, agg);
        else
            k_seg<0,0><<<sgrid, 256, 0, stream>>>(e0, Ce, buf2, offs, ssum, agg);
    }

    hgemm8<1,1,1><<<dim3(2, 79), 512, 0, stream>>>(NN, 512, 512, agg, 512, n2W1et,
        z1, 512, zbias, ubias_n, batch, x, nullptr, n2W1);
    k_final<<<(NN * 64 + 255) / 256, 256, 0, stream>>>(z1, n2W2, n2b2, out);
}

// Round 15
// 2102.018 us; speedup vs baseline: 3.9516x; 1.0280x over previous
//
#include <hip/hip_runtime.h>

typedef _Float16 f16;
typedef __attribute__((ext_vector_type(8))) _Float16 f16x8;
typedef __attribute__((ext_vector_type(4))) float f32x4;

#define E_TOTAL 160000
#define NN 20000
#define NGRAPH 64

__device__ __forceinline__ void gl_lds16(const void* g, void* l) {
    __builtin_amdgcn_global_load_lds((const __attribute__((address_space(1))) void*)g,
                                     (__attribute__((address_space(3))) void*)l, 16, 0, 0);
}

#define MFMA16(a, b, c) __builtin_amdgcn_mfma_f32_16x16x32_f16((a), (b), (c), 0, 0, 0)
#define LGKM(n) do { asm volatile("s_waitcnt lgkmcnt(" #n ")" ::: "memory"); \
                     __builtin_amdgcn_sched_barrier(0); } while (0)
#define VMW4  asm volatile("s_waitcnt vmcnt(4)" ::: "memory")
#define VMW0  asm volatile("s_waitcnt vmcnt(0)" ::: "memory")
#define SBAR  __builtin_amdgcn_s_barrier()
#define SCHED0 __builtin_amdgcn_sched_barrier(0)

// ------------- fp16 MFMA GEMM, 256x256, BK=64, 8 waves, pipelined-lgkm 4-phase, XCD swizzle ----
// (r9/r13/r14 kernel, best measured; FROZEN)
template <int RELU, int AUXU, int AUXX>
__global__ __launch_bounds__(512, 2) void hgemm8(
    int M, int N, int K,
    const f16* __restrict__ A, int lda,
    const f16* __restrict__ Bt,
    f16* __restrict__ C, int ldc,
    const float* __restrict__ bias,
    const f16* __restrict__ utab, const int* __restrict__ uidx,
    const float* __restrict__ x9, const int* __restrict__ xidx, const float* __restrict__ W9)
{
    __shared__ __align__(16) char Ash[2][2][16384];
    __shared__ __align__(16) char Bsh[2][2][16384];
    __shared__ float Ws9[AUXX ? 2304 : 1];   // 9 x 256

    const int tid  = threadIdx.x;
    const int lane = tid & 63;
    const int w    = tid >> 6;

    // T1: bijective XCD-chunked remap (m204), bm-major
    const int nbn = gridDim.x;
    const int nwg = nbn * gridDim.y;
    int d  = blockIdx.y * nbn + blockIdx.x;
    int q8 = nwg >> 3, r8 = nwg & 7;
    int xk = d & 7, j8 = d >> 3;
    int wl = (xk < r8 ? xk * (q8 + 1) : r8 * (q8 + 1) + (xk - r8) * q8) + j8;
    const int bm = (wl / nbn) * 256;
    const int bn = (wl % nbn) * 256;

    const int wm = (w >> 2) * 128;
    const int wn = (w & 3) * 64;
    const int fr = lane & 15;
    const int kq = lane >> 4;

    const char* Ab = (const char*)A;
    const char* Bb = (const char*)Bt;
    const size_t lda2 = (size_t)lda * 2;
    const size_t ldb2 = (size_t)K * 2;

    f32x4 acc[8][4] = {};

    int aoff[8], boff[4];
#pragma unroll
    for (int mi = 0; mi < 8; ++mi) {
        int r = wm + mi * 16 + fr;
        aoff[mi] = r * 64 + ((kq ^ ((r >> 1) & 3)) << 4);
    }
#pragma unroll
    for (int ni = 0; ni < 4; ++ni) {
        int r = wn + ni * 16 + fr;
        boff[ni] = r * 64 + ((kq ^ ((r >> 1) & 3)) << 4);
    }

    int sdest[2];
    size_t gsrcA[2], gsrcB[2];
#pragma unroll
    for (int i = 0; i < 2; ++i) {
        int Lo = i * 8192 + tid * 16;
        int row = Lo >> 6;
        int s = (Lo >> 4) & 3;
        int sw = (s ^ ((row >> 1) & 3)) << 4;
        sdest[i] = Lo;
        gsrcA[i] = (size_t)(bm + row) * lda2 + sw;
        gsrcB[i] = (size_t)(bn + row) * ldb2 + sw;
    }

    const int NT = K >> 6;

    auto stageA = [&](int t, int h, int buf) {
        size_t kb = (size_t)t * 128 + h * 64;
#pragma unroll
        for (int i = 0; i < 2; ++i)
            gl_lds16(Ab + gsrcA[i] + kb, &Ash[buf][h][0] + sdest[i]);
    };
    auto stageB = [&](int t, int h, int buf) {
        size_t kb = (size_t)t * 128 + h * 64;
#pragma unroll
        for (int i = 0; i < 2; ++i)
            gl_lds16(Bb + gsrcB[i] + kb, &Bsh[buf][h][0] + sdest[i]);
    };

    f16x8 a0[4], b0[4], a1[4], a2[4], b2[4], a3[4];

    stageA(0, 0, 0); stageB(0, 0, 0); stageA(0, 1, 0); stageB(0, 1, 0);
    VMW4;
    SBAR;
#pragma unroll
    for (int i = 0; i < 4; ++i) a0[i] = *(const f16x8*)(&Ash[0][0][0] + aoff[i]);
#pragma unroll
    for (int i = 0; i < 4; ++i) b0[i] = *(const f16x8*)(&Bsh[0][0][0] + boff[i]);

    for (int t = 0; t < NT; ++t) {
        const int cur = t & 1, nxt = cur ^ 1;
        const bool pre = (t + 1 < NT);
        const char* A0 = &Ash[cur][0][0];
        const char* A1 = &Ash[cur][1][0];
        const char* B1 = &Bsh[cur][1][0];

#pragma unroll
        for (int i = 0; i < 4; ++i) a1[i] = *(const f16x8*)(A0 + aoff[4 + i]);
        if (pre) stageA(t + 1, 0, nxt);
        SBAR;
        LGKM(4);
        __builtin_amdgcn_s_setprio(1);
#pragma unroll
        for (int mi = 0; mi < 4; ++mi)
#pragma unroll
            for (int ni = 0; ni < 4; ++ni)
                acc[mi][ni] = MFMA16(a0[mi], b0[ni], acc[mi][ni]);
        __builtin_amdgcn_s_setprio(0);
        SBAR;

        if (pre) stageB(t + 1, 0, nxt);
        SBAR;
        LGKM(0);
        if (pre) { VMW4; } else { VMW0; }
        SBAR;
#pragma unroll
        for (int i = 0; i < 4; ++i) a2[i] = *(const f16x8*)(A1 + aoff[i]);
#pragma unroll
        for (int i = 0; i < 4; ++i) b2[i] = *(const f16x8*)(B1 + boff[i]);
        SCHED0;
        __builtin_amdgcn_s_setprio(1);
#pragma unroll
        for (int mi = 0; mi < 4; ++mi)
#pragma unroll
            for (int ni = 0; ni < 4; ++ni)
                acc[4 + mi][ni] = MFMA16(a1[mi], b0[ni], acc[4 + mi][ni]);
        __builtin_amdgcn_s_setprio(0);
        SBAR;

#pragma unroll
        for (int i = 0; i < 4; ++i) a3[i] = *(const f16x8*)(A1 + aoff[4 + i]);
        if (pre) stageA(t + 1, 1, nxt);
        SBAR;
        LGKM(4);
        __builtin_amdgcn_s_setprio(1);
#pragma unroll
        for (int mi = 0; mi < 4; ++mi)
#pragma unroll
            for (int ni = 0; ni < 4; ++ni)
                acc[mi][ni] = MFMA16(a2[mi], b2[ni], acc[mi][ni]);
        __builtin_amdgcn_s_setprio(0);
        SBAR;

        if (pre) stageB(t + 1, 1, nxt);
        SBAR;
        LGKM(0);
        if (pre) {
            VMW4;
            SBAR;
            const char* An = &Ash[nxt][0][0];
            const char* Bn = &Bsh[nxt][0][0];
#pragma unroll
            for (int i = 0; i < 4; ++i) a0[i] = *(const f16x8*)(An + aoff[i]);
#pragma unroll
            for (int i = 0; i < 4; ++i) b0[i] = *(const f16x8*)(Bn + boff[i]);
            SCHED0;
        }
        __builtin_amdgcn_s_setprio(1);
#pragma unroll
        for (int mi = 0; mi < 4; ++mi)
#pragma unroll
            for (int ni = 0; ni < 4; ++ni)
                acc[4 + mi][ni] = MFMA16(a3[mi], b2[ni], acc[4 + mi][ni]);
        __builtin_amdgcn_s_setprio(0);
        SBAR;
    }

    if (AUXX) {
        for (int i = tid; i < 9 * 256; i += 512)
            Ws9[i] = W9[(size_t)(i >> 8) * N + bn + (i & 255)];
        __syncthreads();
    }

    // C/D layout: col = lane&15, row = kq*4 + reg
#pragma unroll
    for (int mi = 0; mi < 8; ++mi) {
        int r0 = bm + wm + mi * 16 + kq * 4;
#pragma unroll
        for (int r = 0; r < 4; ++r) {
            int grow = r0 + r;
            if (grow >= M) continue;
            int ub = 0;
            if (AUXU) ub = uidx[grow];
            float xv[9];
            if (AUXX) {
                int xi = xidx ? xidx[grow] : grow;
#pragma unroll
                for (int q = 0; q < 9; ++q) xv[q] = x9[(size_t)xi * 9 + q];
            }
#pragma unroll
            for (int ni = 0; ni < 4; ++ni) {
                int lcol = wn + ni * 16 + fr;
                int col = bn + lcol;
                float v = acc[mi][ni][r] + bias[col];
                if (AUXU) v += (float)utab[(size_t)ub * N + col];
                if (AUXX) {
                    float s = 0.f;
#pragma unroll
                    for (int q = 0; q < 9; ++q) s = fmaf(xv[q], Ws9[q * 256 + lcol], s);
                    v += s;
                }
                if (RELU) v = fmaxf(v, 0.f);
                C[(size_t)grow * ldc + col] = (f16)v;
            }
        }
    }
}

// ---- merged weight prep: 9 coalesced LDS-tiled transposes + 1 flat f32->f16 copy ----
struct WtJob { const float* src; f16* dst; int r0, ks, n, kp, tr; };
struct WtJobs { WtJob j[10]; };

__global__ __launch_bounds__(256) void k_wtt(WtJobs js)
{
    __shared__ f16 tile[32][33];
    WtJob jb = js.j[blockIdx.y];
    if (!jb.tr) {                      // flat copy (eW5)
        size_t tot = (size_t)jb.n * jb.kp;
        for (size_t i = (size_t)blockIdx.x * 256 + threadIdx.x; i < tot;
             i += (size_t)gridDim.x * 256)
            jb.dst[i] = (f16)jb.src[i];
        return;
    }
    int tilesX = (jb.kp + 31) >> 5;
    int tilesY = (jb.n + 31) >> 5;
    int tl = blockIdx.x;
    if (tl >= tilesX * tilesY) return;
    int k0 = (tl % tilesX) << 5;
    int n0 = (tl / tilesX) << 5;
    int tx = threadIdx.x & 31, ty = threadIdx.x >> 5;
#pragma unroll
    for (int i = 0; i < 4; ++i) {
        int k = k0 + ty + i * 8;
        int n = n0 + tx;
        float v = (k < jb.ks && n < jb.n) ? jb.src[(size_t)(jb.r0 + k) * jb.n + n] : 0.f;
        tile[ty + i * 8][tx] = (f16)v;
    }
    __syncthreads();
#pragma unroll
    for (int i = 0; i < 4; ++i) {
        int n = n0 + ty + i * 8;
        int k = k0 + tx;
        if (n < jb.n && k < jb.kp)
            jb.dst[(size_t)n * jb.kp + k] = tile[tx][ty + i * 8];
    }
}

__global__ void k_cbias(const float* __restrict__ n1W1, const float* __restrict__ eb5,
                        const float* __restrict__ n1b1, float* __restrict__ cb)
{
    int b = blockIdx.x * 256 + threadIdx.x;
    if (b >= 512) return;
    float s = n1b1[b];
    for (int c = 0; c < 512; ++c) s = fmaf(eb5[c], n1W1[(size_t)(9 + c) * 512 + b], s);
    cb[b] = s;
}

__global__ __launch_bounds__(256) void k_u2b(const float* __restrict__ u,
                                             const float* __restrict__ Wsel,
                                             const float* __restrict__ bsel,
                                             f16* __restrict__ u2h)
{
    __shared__ float us[4096];
    __shared__ float red[256];
    const int g = blockIdx.y;
    const int c0 = blockIdx.x * 16;
    const int col = threadIdx.x & 15;
    const int kp = threadIdx.x >> 4;
    for (int i = threadIdx.x; i < 4096; i += 256) us[i] = u[(size_t)g * 4096 + i];
    __syncthreads();
    float acc = 0.f;
    const float* wp = Wsel + (size_t)(kp * 256) * 256 + c0 + col;
#pragma unroll 8
    for (int i = 0; i < 256; ++i) acc = fmaf(us[kp * 256 + i], wp[(size_t)i * 256], acc);
    red[threadIdx.x] = acc;
    __syncthreads();
    if (kp < 8) red[threadIdx.x] += red[threadIdx.x + 128];
    __syncthreads();
    if (kp < 4) red[threadIdx.x] += red[threadIdx.x + 64];
    __syncthreads();
    if (kp < 2) red[threadIdx.x] += red[threadIdx.x + 32];
    __syncthreads();
    if (kp == 0)
        u2h[(size_t)g * 256 + c0 + col] = (f16)(red[threadIdx.x] + red[threadIdx.x + 16] + bsel[c0 + col]);
}

__global__ void k_cnt(const int* __restrict__ ei, float* __restrict__ cnt)
{
    int t = blockIdx.x * 256 + threadIdx.x;
    if (t < E_TOTAL) atomicAdd(cnt + ei[t], 1.0f);
}

// ---- exclusive scan of cnt -> offs[NN+1], cursor copy ----
__global__ __launch_bounds__(256) void k_scan(const float* __restrict__ cnt,
                                              int* __restrict__ offs, int* __restrict__ cursor)
{
    __shared__ int part[256];
    const int tid = threadIdx.x;
    const int n0 = tid * 79;
    int s = 0;
    for (int i = 0; i < 79; ++i) {
        int n = n0 + i;
        if (n < NN) s += (int)cnt[n];
    }
    part[tid] = s;
    __syncthreads();
    for (int dstep = 1; dstep < 256; dstep <<= 1) {
        int add = (tid >= dstep) ? part[tid - dstep] : 0;
        __syncthreads();
        part[tid] += add;
        __syncthreads();
    }
    int run = part[tid] - s;
    for (int i = 0; i < 79; ++i) {
        int n = n0 + i;
        if (n < NN) {
            offs[n] = run;
            cursor[n] = run;
            run += (int)cnt[n];
        }
    }
    if (tid == 255) offs[NN] = E_TOTAL;
}

__global__ void k_perm(const int* __restrict__ ei, int* __restrict__ cursor,
                       int* __restrict__ perm)
{
    int e = blockIdx.x * 256 + threadIdx.x;
    if (e < E_TOTAL) {
        int pos = atomicAdd(cursor + ei[e], 1);
        perm[pos] = e;
    }
}

// ---- per-edge gather (1 thread/edge, vectorized f16x8 stores) ----
__global__ void k_gather19(const float* __restrict__ x, const float* __restrict__ eattr,
                           const int* __restrict__ ei, const int* __restrict__ batch,
                           const int* __restrict__ perm,
                           f16* __restrict__ feat, int* __restrict__ ebat, int* __restrict__ colA)
{
    int j = blockIdx.x * 256 + threadIdx.x;
    if (j >= E_TOTAL) return;
    int e = perm[j];
    int row = ei[e], col = ei[E_TOTAL + e];
    f16 v[64];
#pragma unroll
    for (int q = 0; q < 9; ++q) v[q] = (f16)x[(size_t)row * 9 + q];
#pragma unroll
    for (int q = 0; q < 9; ++q) v[9 + q] = (f16)x[(size_t)col * 9 + q];
    v[18] = (f16)eattr[e];
#pragma unroll
    for (int q = 19; q < 64; ++q) v[q] = (f16)0.f;
    f16* dst = feat + (size_t)j * 64;
#pragma unroll
    for (int q = 0; q < 8; ++q)
        *(f16x8*)(dst + q * 8) = *(const f16x8*)(v + q * 8);
    ebat[j] = batch[row];
    colA[j] = col;
}

// ---- segmented sum of sorted h2 rows into ssum; FIRST: overwrite; LAST: emit agg ----
template <int FIRST, int LAST>
__global__ void k_seg(int e0, int Ce, const f16* __restrict__ h2,
                      const int* __restrict__ offs, float* __restrict__ ssum,
                      f16* __restrict__ agg)
{
    size_t t = (size_t)blockIdx.x * 256 + threadIdx.x;
    if (t >= (size_t)NN * 512) return;
    int n = (int)(t >> 9), col = (int)(t & 511);
    int lo0 = offs[n], hi0 = offs[n + 1];
    int lo = lo0, hi = hi0;
    int e1 = e0 + Ce;
    if (lo < e0) lo = e0;
    if (hi > e1) hi = e1;
    float s = 0.f;
    for (int j = lo; j < hi; ++j)
        s += (float)h2[(size_t)(j - e0) * 512 + col];
    if (LAST) {
        float tot = (FIRST ? 0.f : ssum[t]) + s;
        agg[t] = (f16)(tot / fmaxf((float)(hi0 - lo0), 1.f));
    } else if (FIRST) {
        ssum[t] = s;
    } else if (lo < hi) {
        ssum[t] += s;
    }
}

__global__ void k_final(const f16* __restrict__ z1, const float* __restrict__ W,
                        const float* __restrict__ b, float* __restrict__ out)
{
    int gt = blockIdx.x * 256 + threadIdx.x;
    int row = gt >> 6;
    int lane = threadIdx.x & 63;
    if (row >= NN) return;
    float s = 0.f;
#pragma unroll
    for (int c = lane; c < 512; c += 64) s += (float)z1[(size_t)row * 512 + c] * W[c];
#pragma unroll
    for (int off = 32; off; off >>= 1) s += __shfl_down(s, off);
    if (lane == 0) out[row] = s + b[0];
}

// ---------------- launch ----------------

extern "C" void kernel_launch(void* const* d_in, const int* in_sizes, int n_in,
                              void* d_out, int out_size, void* d_ws, size_t ws_size,
                              hipStream_t stream)
{
    const float* x     = (const float*)d_in[0];
    const float* eattr = (const float*)d_in[1];
    const float* u     = (const float*)d_in[2];
    const int*   ei    = (const int*)d_in[3];
    const int*   batch = (const int*)d_in[4];
    const float* Wsel  = (const float*)d_in[5];
    const float* bsel  = (const float*)d_in[6];
    const float* eW1 = (const float*)d_in[7],  * eb1 = (const float*)d_in[8];
    const float* eW2 = (const float*)d_in[9],  * eb2 = (const float*)d_in[10];
    const float* eW3 = (const float*)d_in[11], * eb3 = (const float*)d_in[12];
    const float* eW4 = (const float*)d_in[13], * eb4 = (const float*)d_in[14];
    const float* eW5 = (const float*)d_in[15], * eb5 = (const float*)d_in[16];
    const float* n1W1 = (const float*)d_in[17], * n1b1 = (const float*)d_in[18];
    const float* n1W2 = (const float*)d_in[19], * n1b2 = (const float*)d_in[20];
    const float* n2W1 = (const float*)d_in[21], * n2b1 = (const float*)d_in[22];
    const float* n2W2 = (const float*)d_in[23], * n2b2 = (const float*)d_in[24];
    float* out = (float*)d_out;

    char* ws = (char*)d_ws;
    size_t off = 0;
    auto alc = [&](size_t bytes) { char* p = ws + off; off += (bytes + 255) & ~(size_t)255; return p; };

    float* ssum  = (float*)alc((size_t)NN * 512 * 4);
    float* cnt   = (float*)alc((size_t)NN * 4);
    float* zbias = (float*)alc(1024 * 4);
    float* cbias = (float*)alc(512 * 4);
    f16* u2h     = (f16*)alc((size_t)256 * 256 * 2);
    f16* ubias_e = (f16*)alc((size_t)64 * 1024 * 2);
    f16* ubias_n = (f16*)alc((size_t)64 * 512 * 2);
    f16* eW1t19  = (f16*)alc((size_t)1024 * 64 * 2);
    f16* eW1ut   = (f16*)alc((size_t)1024 * 256 * 2);
    f16* eW2t    = (f16*)alc((size_t)1024 * 1024 * 2);
    f16* eW3t    = (f16*)alc((size_t)1024 * 1024 * 2);
    f16* eW4t    = (f16*)alc((size_t)1024 * 1024 * 2);
    f16* eW5h    = (f16*)alc((size_t)1024 * 512 * 2);
    f16* combo_t = (f16*)alc((size_t)512 * 1024 * 2);
    f16* n1W1et  = (f16*)alc((size_t)512 * 512 * 2);
    f16* n1W2t   = (f16*)alc((size_t)512 * 512 * 2);
    f16* n2W1et  = (f16*)alc((size_t)512 * 512 * 2);
    f16* n2W1ut  = (f16*)alc((size_t)512 * 256 * 2);
    int* offs    = (int*)alc((size_t)(NN + 1) * 4);
    int* cursor  = (int*)alc((size_t)NN * 4);
    int* perm    = (int*)alc((size_t)E_TOTAL * 4);
    f16* featAll = (f16*)alc((size_t)E_TOTAL * 64 * 2);
    int* ebatAll = (int*)alc((size_t)E_TOTAL * 4);
    int* colAll  = (int*)alc((size_t)E_TOTAL * 4);
    size_t fixed = off;

    size_t per_edge = 4096;
    size_t need_ro = (size_t)20224 * 512 * 2 * 2;
    size_t avail = ws_size > fixed ? ws_size - fixed : 0;
    long long Cmax = (long long)(avail / per_edge);
    int C;
    if (Cmax >= E_TOTAL)      C = E_TOTAL;
    else if (Cmax >= 16384)   C = (int)((Cmax / 16384) * 16384);
    else                      C = (int)((Cmax / 256) * 256);
    if ((size_t)C * per_edge < need_ro)
        C = (int)(((need_ro + per_edge - 1) / per_edge + 255) / 256 * 256);

    f16* buf1 = (f16*)(ws + fixed);
    f16* buf2 = buf1 + (size_t)C * 1024;
    f16* agg  = (f16*)(ws + fixed);            // alias over buf1 (written by last k_seg)
    f16* z1   = agg + (size_t)20224 * 512;

    // zero only cnt + zbias
    size_t zlen = (size_t)((char*)zbias - (char*)cnt) + 1024 * 4;
    hipMemsetAsync(cnt, 0, zlen, stream);

    WtJobs js;
    js.j[0] = {eW1,  eW1t19, 0,   19,   1024, 64,   1};
    js.j[1] = {eW1,  eW1ut,  19,  256,  1024, 256,  1};
    js.j[2] = {eW2,  eW2t,   0,   1024, 1024, 1024, 1};
    js.j[3] = {eW3,  eW3t,   0,   1024, 1024, 1024, 1};
    js.j[4] = {eW4,  eW4t,   0,   1024, 1024, 1024, 1};
    js.j[5] = {n1W1, n1W1et, 9,   512,  512,  512,  1};
    js.j[6] = {n1W2, n1W2t,  0,   512,  512,  512,  1};
    js.j[7] = {n2W1, n2W1et, 9,   512,  512,  512,  1};
    js.j[8] = {n2W1, n2W1ut, 521, 256,  512,  256,  1};
    js.j[9] = {eW5,  eW5h,   0,   0,    1024, 512,  0};   // flat copy
    k_wtt<<<dim3(1024, 10), 256, 0, stream>>>(js);

    k_u2b<<<dim3(16, NGRAPH), 256, 0, stream>>>(u, Wsel, bsel, u2h);
    k_cnt<<<(E_TOTAL + 255) / 256, 256, 0, stream>>>(ei, cnt);
    k_scan<<<1, 256, 0, stream>>>(cnt, offs, cursor);
    k_perm<<<(E_TOTAL + 255) / 256, 256, 0, stream>>>(ei, cursor, perm);
    k_cbias<<<2, 256, 0, stream>>>(n1W1, eb5, n1b1, cbias);
    k_gather19<<<(E_TOTAL + 255) / 256, 256, 0, stream>>>(
        x, eattr, ei, batch, perm, featAll, ebatAll, colAll);

    hgemm8<0,0,0><<<dim3(4, 1), 512, 0, stream>>>(64, 1024, 256, u2h, 256, eW1ut,
        ubias_e, 1024, eb1, nullptr, nullptr, nullptr, nullptr, nullptr);
    hgemm8<0,0,0><<<dim3(2, 1), 512, 0, stream>>>(64, 512, 256, u2h, 256, n2W1ut,
        ubias_n, 512, n2b1, nullptr, nullptr, nullptr, nullptr, nullptr);

    hgemm8<0,0,0><<<dim3(4, 2), 512, 0, stream>>>(512, 1024, 512, n1W1et, 512, eW5h,
        combo_t, 1024, zbias, nullptr, nullptr, nullptr, nullptr, nullptr);

    for (int e0 = 0; e0 < E_TOTAL; e0 += C) {
        int Ce = E_TOTAL - e0 < C ? E_TOTAL - e0 : C;
        int gy = (Ce + 255) / 256;
        bool first = (e0 == 0);
        bool last  = (e0 + Ce >= E_TOTAL);

        hgemm8<1,1,0><<<dim3(4, gy), 512, 0, stream>>>(Ce, 1024, 64,
            featAll + (size_t)e0 * 64, 64, eW1t19,
            buf1, 1024, zbias, ubias_e, ebatAll + e0, nullptr, nullptr, nullptr);
        hgemm8<1,0,0><<<dim3(4, gy), 512, 0, stream>>>(Ce, 1024, 1024, buf1, 1024, eW2t,
            buf2, 1024, eb2, nullptr, nullptr, nullptr, nullptr, nullptr);
        hgemm8<1,0,0><<<dim3(4, gy), 512, 0, stream>>>(Ce, 1024, 1024, buf2, 1024, eW3t,
            buf1, 1024, eb3, nullptr, nullptr, nullptr, nullptr, nullptr);
        hgemm8<1,0,0><<<dim3(4, gy), 512, 0, stream>>>(Ce, 1024, 1024, buf1, 1024, eW4t,
            buf2, 1024, eb4, nullptr, nullptr, nullptr, nullptr, nullptr);

        // h1 = relu(x[col]@n1W1[0:9] + (buf2)@combo + cbias)
        hgemm8<1,0,1><<<dim3(2, gy), 512, 0, stream>>>(Ce, 512, 1024, buf2, 1024, combo_t,
            buf1, 512, cbias, nullptr, nullptr, x, colAll + e0, n1W1);

        // h2 = relu(h1@n1W2 + n1b2) -> buf2 (plain write; edges sorted by dest node)
        hgemm8<1,0,0><<<dim3(2, gy), 512, 0, stream>>>(Ce, 512, 512, buf1, 512, n1W2t,
            buf2, 512, n1b2, nullptr, nullptr, nullptr, nullptr, nullptr);

        unsigned sgrid = (unsigned)(((size_t)NN * 512 + 255) / 256);
        if (first && last)
            k_seg<1,1><<<sgrid, 256, 0, stream>>>(e0, Ce, buf2, offs, ssum, agg);
        else if (first)
            k_seg<1,0><<<sgrid, 256, 0, stream>>>(e0, Ce, buf2, offs, ssum, agg);
        else if (last)
            k_seg<0,1><<<sgrid, 256, 0, stream>>>(e0, Ce, buf2, offs, ssum, agg);
        else
            k_seg<0,0><<<sgrid, 256, 0, stream>>>(e0, Ce, buf2, offs, ssum, agg);
    }

    hgemm8<1,1,1><<<dim3(2, 79), 512, 0, stream>>>(NN, 512, 512, agg, 512, n2W1et,
        z1, 512, zbias, ubias_n, batch, x, nullptr, n2W1);
    k_final<<<(NN * 64 + 255) / 256, 256, 0, stream>>>(z1, n2W2, n2b2, out);
}